// Round 10
// baseline (713.094 us; speedup 1.0000x reference)
//
#include <hip/hip_runtime.h>
#include <math.h>

typedef __attribute__((ext_vector_type(8))) short short8;
typedef __attribute__((ext_vector_type(8))) unsigned short ushort8;
typedef __attribute__((ext_vector_type(4))) unsigned short ushort4v;
typedef __attribute__((ext_vector_type(4))) float f32x4;
typedef __attribute__((ext_vector_type(16))) float f32x16;

#define NPTS  20000
#define NQ    100000
#define TOK   1024
#define DIMD  256
#define NHD   8
#define NLAY  5
#define GRD   4096
#define CAP   512
#define QN    32

#define XMINF (-2.0f)
#define YMINF (-1.5f)
#define CELL  0.15f
#define NCX   40
#define NCY   20
#define NCELL 800

#define MFMA(a,b,c)   __builtin_amdgcn_mfma_f32_16x16x32_bf16(a,b,c,0,0,0)
#define MFMA32(a,b,c) __builtin_amdgcn_mfma_f32_32x32x16_bf16(a,b,c,0,0,0)

__device__ inline void split2(float x, ushort& h, ushort& l) {
  unsigned u = __float_as_uint(x);
  unsigned hr = (u + 0x7FFFu + ((u >> 16) & 1u)) & 0xFFFF0000u;
  h = (ushort)(hr >> 16);
  float r = x - __uint_as_float(hr);
  unsigned u2 = __float_as_uint(r);
  l = (ushort)((u2 + 0x7FFFu + ((u2 >> 16) & 1u)) >> 16);
}

__device__ inline ushort bf16of(float x) {
  unsigned u = __float_as_uint(x);
  return (ushort)((u + 0x7FFFu + ((u >> 16) & 1u)) >> 16);
}

// ---------------------------------------------------------------------------
// Point binning
// ---------------------------------------------------------------------------
__device__ inline int cell_of(float px, float py) {
  int cx = (int)floorf((px - XMINF) / CELL);
  int cy = (int)floorf((py - YMINF) / CELL);
  cx = min(max(cx, 0), NCX - 1);
  cy = min(max(cy, 0), NCY - 1);
  return cy * NCX + cx;
}

__global__ void k_zero(int* __restrict__ cnt) {
  int i = blockIdx.x * 256 + threadIdx.x;
  if (i < NCELL) cnt[i] = 0;
}

__global__ void k_bincount(const float* __restrict__ pts, int* __restrict__ cnt) {
  int p = blockIdx.x * 256 + threadIdx.x;
  if (p < NPTS) atomicAdd(&cnt[cell_of(pts[p*2], pts[p*2+1])], 1);
}

__global__ void k_prefix(const int* __restrict__ cnt, int* __restrict__ start,
                         int* __restrict__ cursor) {
  __shared__ int s[1024];
  int t = threadIdx.x;
  int v0 = (t < NCELL) ? cnt[t] : 0;
  s[t] = v0;
  __syncthreads();
  for (int off = 1; off < 1024; off <<= 1) {
    int v = (t >= off) ? s[t - off] : 0;
    __syncthreads();
    s[t] += v;
    __syncthreads();
  }
  int ex = s[t] - v0;
  if (t < NCELL) { start[t] = ex; cursor[t] = ex; }
  if (t == 0) start[NCELL] = NPTS;
}

__global__ void k_scatter(const float* __restrict__ pts, int* __restrict__ cursor,
                          float* __restrict__ bpx, float* __restrict__ bpy,
                          int* __restrict__ bpi) {
  int p = blockIdx.x * 256 + threadIdx.x;
  if (p < NPTS) {
    float px = pts[p*2], py = pts[p*2+1];
    int slot = atomicAdd(&cursor[cell_of(px, py)], 1);
    bpx[slot] = px; bpy[slot] = py; bpi[slot] = p;
  }
}

// ---------------------------------------------------------------------------
// Encode
// ---------------------------------------------------------------------------
__global__ void k_encode(const float* __restrict__ bpx, const float* __restrict__ bpy,
                         const int* __restrict__ bpi, const int* __restrict__ cellstart,
                         const float* __restrict__ grd,
                         const float* __restrict__ w1, const float* __restrict__ b1,
                         const float* __restrict__ w2, const float* __restrict__ b2,
                         ushort* __restrict__ fH, ushort* __restrict__ fL) {
  __shared__ float s_d2[CAP], s_px[CAP], s_py[CAP];
  __shared__ int   s_idx[CAP];
  __shared__ int   s_cnt;
  __shared__ float s_selx[32], s_sely[32];
  __shared__ float s_part[4][64];

  int gi = blockIdx.x, sc = blockIdx.y;
  int tid = threadIdx.x;
  const float radius = (sc == 0) ? 0.15f : 0.30f;
  const int   K      = (sc == 0) ? 16 : 32;
  float gx = grd[gi*2+0], gy = grd[gi*2+1];
  float g2 = __fadd_rn(__fmul_rn(gx,gx), __fmul_rn(gy,gy));
  float r2 = __fmul_rn(radius, radius);

  if (tid == 0) s_cnt = 0;
  __syncthreads();

  int cx0 = min(max((int)floorf((gx - radius - XMINF) / CELL), 0), NCX - 1);
  int cx1 = min(max((int)floorf((gx + radius - XMINF) / CELL), 0), NCX - 1);
  int cy0 = min(max((int)floorf((gy - radius - YMINF) / CELL), 0), NCY - 1);
  int cy1 = min(max((int)floorf((gy + radius - YMINF) / CELL), 0), NCY - 1);

  for (int cy = cy0; cy <= cy1; ++cy) {
    int b0 = cellstart[cy*NCX + cx0];
    int b1 = cellstart[cy*NCX + cx1 + 1];
    for (int i = b0 + tid; i < b1; i += 256) {
      float px = bpx[i], py = bpy[i];
      float p2  = __fadd_rn(__fmul_rn(px,px), __fmul_rn(py,py));
      float dot = __fadd_rn(__fmul_rn(gx,px), __fmul_rn(gy,py));
      float d2  = __fsub_rn(__fadd_rn(g2,p2), __fmul_rn(2.0f,dot));
      if (d2 < r2) {
        int pos = atomicAdd(&s_cnt, 1);
        if (pos < CAP) { s_d2[pos] = d2; s_px[pos] = px; s_py[pos] = py; s_idx[pos] = bpi[i]; }
      }
    }
  }
  __syncthreads();
  int m = min(s_cnt, CAP);
  int nsel;

  if (m > K) {
    for (int i = tid; i < m; i += 256) {
      float di = s_d2[i];
      int   pi = s_idx[i];
      int rank = 0;
      for (int j = 0; j < m; ++j) {
        float dj = s_d2[j];
        rank += (dj < di || (dj == di && s_idx[j] < pi)) ? 1 : 0;
      }
      if (rank < K) { s_selx[rank] = s_px[i]; s_sely[rank] = s_py[i]; }
    }
    nsel = K;
  } else {
    if (tid < m) { s_selx[tid] = s_px[tid]; s_sely[tid] = s_py[tid]; }
    nsel = m;
  }
  __syncthreads();

  int grp = tid >> 6, d = tid & 63;
  s_part[grp][d] = -INFINITY;
  __syncthreads();
  const float* W1 = w1 + sc*64;
  const float* B1 = b1 + sc*32;
  const float* W2 = w2 + sc*2048;
  const float* B2 = b2 + sc*64;
  for (int base = 0; base < nsel; base += 4) {
    int pi = base + grp;
    if (pi < nsel) {
      float rx = s_selx[pi] - gx;
      float ry = s_sely[pi] - gy;
      float f = B2[d];
      #pragma unroll
      for (int j = 0; j < 32; ++j) {
        float h = rx * W1[j] + ry * W1[32 + j] + B1[j];
        h = fmaxf(h, 0.0f);
        f += h * W2[j*64 + d];
      }
      s_part[grp][d] = fmaxf(s_part[grp][d], f);
    }
  }
  __syncthreads();
  if (tid < 64) {
    float v = fmaxf(fmaxf(s_part[0][tid], s_part[1][tid]),
                    fmaxf(s_part[2][tid], s_part[3][tid]));
    if (nsel == 0) v = 0.0f;
    ushort h, l; split2(v, h, l);
    fH[gi*128 + sc*64 + tid] = h;
    fL[gi*128 + sc*64 + tid] = l;
  }
}

// ---------------------------------------------------------------------------
// f32 tiled GEMM (Wcomb precompute only)
// ---------------------------------------------------------------------------
__global__ void k_gemm(const float* __restrict__ A, const float* __restrict__ B,
                       float* __restrict__ C, int M, int N, int K) {
  __shared__ float As[32][33];
  __shared__ float Bs[32][33];
  int bm = blockIdx.y * 32, bn = blockIdx.x * 32;
  int tx = threadIdx.x & 31, ty = threadIdx.x >> 5;
  float acc[4] = {0.f, 0.f, 0.f, 0.f};
  for (int k0 = 0; k0 < K; k0 += 32) {
    for (int i = threadIdx.x; i < 1024; i += 256) {
      int r = i >> 5, c = i & 31;
      As[r][c] = A[(size_t)(bm + r)*K + k0 + c];
      Bs[r][c] = B[(size_t)(k0 + r)*N + bn + c];
    }
    __syncthreads();
    #pragma unroll
    for (int kk = 0; kk < 32; ++kk) {
      float bv = Bs[kk][tx];
      #pragma unroll
      for (int i = 0; i < 4; ++i) acc[i] += As[ty + 8*i][kk] * bv;
    }
    __syncthreads();
  }
  #pragma unroll
  for (int i = 0; i < 4; ++i)
    C[(size_t)(bm + ty + 8*i)*N + bn + tx] = acc[i];
}

__global__ void k_beff(const float* __restrict__ db1, const float* __restrict__ pb2,
                       const float* __restrict__ dw1, float* __restrict__ b2eff) {
  __shared__ float red[8][32];
  int n0 = blockIdx.x * 32;
  int t = threadIdx.x;
  int nn = t & 31, jc = t >> 5;
  float a = 0.f;
  for (int j = jc*64; j < jc*64 + 64; ++j)
    a += pb2[j] * dw1[(size_t)(256 + j)*256 + n0 + nn];
  red[jc][nn] = a;
  __syncthreads();
  if (t < 32) {
    float s = db1[n0 + t];
    #pragma unroll
    for (int w = 0; w < 8; ++w) s += red[w][t];
    b2eff[n0 + t] = s;
  }
}

__global__ void k_dw2t(const float* __restrict__ dw2,
                       ushort* __restrict__ tH, ushort* __restrict__ tL) {
  int k = threadIdx.x;
  #pragma unroll
  for (int d = 0; d < 16; ++d) {
    float v = (d < 4) ? dw2[k*4 + d] : 0.f;
    ushort h, l; split2(v, h, l);
    tH[d*256 + k] = h; tL[d*256 + k] = l;
  }
}

// ---------------------------------------------------------------------------
// Split+transpose weights
// ---------------------------------------------------------------------------
struct SDesc { const float* src; ushort* dh; ushort* dl; int K, N, Kp, blk0; };
struct STable { int nw; SDesc d[31]; };

__global__ void k_splitT_all(STable tab) {
  __shared__ float tile[32][33];
  int b = blockIdx.x;
  int w = 0;
  for (int i = 1; i < tab.nw; ++i) if (b >= tab.d[i].blk0) w = i;
  SDesc s = tab.d[w];
  int rel = b - s.blk0;
  int ntn = s.N >> 5;
  int tk = rel / ntn, tn = rel - tk*ntn;
  int r = threadIdx.x >> 5, c = threadIdx.x & 31;
  #pragma unroll
  for (int i = 0; i < 4; ++i) {
    int kk = tk*32 + r + i*8;
    tile[r + i*8][c] = (kk < s.K) ? s.src[(size_t)kk*s.N + tn*32 + c] : 0.f;
  }
  __syncthreads();
  #pragma unroll
  for (int i = 0; i < 4; ++i) {
    int nn = tn*32 + r + i*8;
    float v = tile[c][r + i*8];
    ushort hh, ll; split2(v, hh, ll);
    size_t o = (size_t)nn*s.Kp + tk*32 + c;
    s.dh[o] = hh; s.dl[o] = ll;
  }
}

// ---------------------------------------------------------------------------
// Split-bf16 MFMA GEMM, tile (MT*16)x64. Optional split shadow write of C.
// ---------------------------------------------------------------------------
template<bool BIAS, bool RESID, bool WSPLIT, int MT>
__global__ __launch_bounds__(256,2)
void k_mgemm64(const ushort* __restrict__ Ah, const ushort* __restrict__ Al,
               const ushort* __restrict__ Bh, const ushort* __restrict__ Bl,
               const float* __restrict__ bias, const float* __restrict__ resid,
               float* __restrict__ C, int M, int N, int K,
               ushort* __restrict__ wsH, ushort* __restrict__ wsL) {
  __shared__ ushort sAh[MT*16*40], sAl[MT*16*40], sBh[64*40], sBl[64*40];
  int tid = threadIdx.x;
  int wave = tid >> 6, lane = tid & 63, l15 = lane & 15, lhi = lane >> 4;
  int bm = blockIdx.y * (MT*16), bn = blockIdx.x * 64;
  int sr = tid >> 2, sg = (tid & 3) * 8;
  const size_t boff = (size_t)(bn + sr) * K + sg;
  f32x4 acc[MT];
  #pragma unroll
  for (int m = 0; m < MT; ++m) acc[m] = (f32x4){0.f,0.f,0.f,0.f};

  for (int k0 = 0; k0 < K; k0 += 32) {
    __syncthreads();
    if (MT == 4) {
      const size_t aoff = (size_t)(bm + sr) * K + sg;
      *(ushort8*)(sAh + sr*40 + sg) = *(const ushort8*)(Ah + aoff + k0);
      *(ushort8*)(sAl + sr*40 + sg) = *(const ushort8*)(Al + aoff + k0);
    } else {
      int ar = (tid & 127) >> 2, ag = (tid & 3) * 8;
      const ushort* src = (tid < 128) ? Ah : Al;
      ushort* dst = (tid < 128) ? sAh : sAl;
      *(ushort8*)(dst + ar*40 + ag) = *(const ushort8*)(src + (size_t)(bm + ar)*K + k0 + ag);
    }
    *(ushort8*)(sBh + sr*40 + sg) = *(const ushort8*)(Bh + boff + k0);
    *(ushort8*)(sBl + sr*40 + sg) = *(const ushort8*)(Bl + boff + k0);
    __syncthreads();
    short8 ah[MT], al[MT];
    #pragma unroll
    for (int m = 0; m < MT; ++m) {
      int r = m*16 + l15;
      ah[m] = *(const short8*)(sAh + r*40 + lhi*8);
      al[m] = *(const short8*)(sAl + r*40 + lhi*8);
    }
    int rb = wave*16 + l15;
    short8 bh = *(const short8*)(sBh + rb*40 + lhi*8);
    short8 bl = *(const short8*)(sBl + rb*40 + lhi*8);
    #pragma unroll
    for (int m = 0; m < MT; ++m) {
      acc[m] = MFMA(ah[m], bh, acc[m]);
      acc[m] = MFMA(al[m], bh, acc[m]);
      acc[m] = MFMA(ah[m], bl, acc[m]);
    }
  }

  int gc = bn + wave*16 + l15;
  float bv = BIAS ? bias[gc] : 0.f;
  #pragma unroll
  for (int m = 0; m < MT; ++m) {
    int gr0 = bm + m*16 + lhi*4;
    #pragma unroll
    for (int r = 0; r < 4; ++r) {
      size_t idx = (size_t)(gr0 + r)*N + gc;
      float v = acc[m][r] + bv;
      if (RESID) v += resid[idx];
      C[idx] = v;
      if (WSPLIT) {
        ushort hh, ll; split2(v, hh, ll);
        wsH[idx] = hh; wsL[idx] = ll;
      }
    }
  }
}

// ---------------------------------------------------------------------------
// inproj GEMM with fused patch-gather epilogue -> xp split
// ---------------------------------------------------------------------------
__global__ __launch_bounds__(256,2)
void k_inproj(const ushort* __restrict__ Ah, const ushort* __restrict__ Al,
              const ushort* __restrict__ Bh, const ushort* __restrict__ Bl,
              const float* __restrict__ bias,
              ushort* __restrict__ xH, ushort* __restrict__ xL) {
  __shared__ ushort sAh[64*40], sAl[64*40], sBh[64*40], sBl[64*40];
  int tid = threadIdx.x;
  int wave = tid >> 6, lane = tid & 63, l15 = lane & 15, lhi = lane >> 4;
  int bm = blockIdx.y * 64, bn = blockIdx.x * 64;
  int sr = tid >> 2, sg = (tid & 3) * 8;
  const int K = 128;
  const size_t aoff = (size_t)(bm + sr) * K + sg;
  const size_t boff = (size_t)(bn + sr) * K + sg;
  f32x4 acc[4];
  #pragma unroll
  for (int m = 0; m < 4; ++m) acc[m] = (f32x4){0.f,0.f,0.f,0.f};

  for (int k0 = 0; k0 < K; k0 += 32) {
    __syncthreads();
    *(ushort8*)(sAh + sr*40 + sg) = *(const ushort8*)(Ah + aoff + k0);
    *(ushort8*)(sAl + sr*40 + sg) = *(const ushort8*)(Al + aoff + k0);
    *(ushort8*)(sBh + sr*40 + sg) = *(const ushort8*)(Bh + boff + k0);
    *(ushort8*)(sBl + sr*40 + sg) = *(const ushort8*)(Bl + boff + k0);
    __syncthreads();
    short8 ah[4], al[4];
    #pragma unroll
    for (int m = 0; m < 4; ++m) {
      int r = m*16 + l15;
      ah[m] = *(const short8*)(sAh + r*40 + lhi*8);
      al[m] = *(const short8*)(sAl + r*40 + lhi*8);
    }
    int rb = wave*16 + l15;
    short8 bh = *(const short8*)(sBh + rb*40 + lhi*8);
    short8 bl = *(const short8*)(sBl + rb*40 + lhi*8);
    #pragma unroll
    for (int m = 0; m < 4; ++m) {
      acc[m] = MFMA(ah[m], bh, acc[m]);
      acc[m] = MFMA(al[m], bh, acc[m]);
      acc[m] = MFMA(ah[m], bl, acc[m]);
    }
  }

  int gc = bn + wave*16 + l15;
  float bv = bias[gc];
  #pragma unroll
  for (int m = 0; m < 4; ++m) {
    int gr0 = bm + m*16 + lhi*4;
    #pragma unroll
    for (int r = 0; r < 4; ++r) {
      int g = gr0 + r;
      int y = g >> 6, x = g & 63;
      int t = (y >> 1)*32 + (x >> 1);
      int f = gc*4 + (y & 1)*2 + (x & 1);
      float v = acc[m][r] + bv;
      ushort hh, ll; split2(v, hh, ll);
      size_t o = (size_t)t*1024 + f;
      xH[o] = hh; xL[o] = ll;
    }
  }
}

// ---------------------------------------------------------------------------
// unpatch GEMM with fused unpatch epilogue -> pr split
// ---------------------------------------------------------------------------
__global__ __launch_bounds__(256,2)
void k_upgemm(const ushort* __restrict__ Ah, const ushort* __restrict__ Al,
              const ushort* __restrict__ Bh, const ushort* __restrict__ Bl,
              const float* __restrict__ bias,
              ushort* __restrict__ pH, ushort* __restrict__ pL) {
  __shared__ ushort sAh[64*40], sAl[64*40], sBh[64*40], sBl[64*40];
  int tid = threadIdx.x;
  int wave = tid >> 6, lane = tid & 63, l15 = lane & 15, lhi = lane >> 4;
  int bm = blockIdx.y * 64, bn = blockIdx.x * 64;
  int sr = tid >> 2, sg = (tid & 3) * 8;
  const int K = 256;
  const size_t aoff = (size_t)(bm + sr) * K + sg;
  const size_t boff = (size_t)(bn + sr) * K + sg;
  f32x4 acc[4];
  #pragma unroll
  for (int m = 0; m < 4; ++m) acc[m] = (f32x4){0.f,0.f,0.f,0.f};

  for (int k0 = 0; k0 < K; k0 += 32) {
    __syncthreads();
    *(ushort8*)(sAh + sr*40 + sg) = *(const ushort8*)(Ah + aoff + k0);
    *(ushort8*)(sAl + sr*40 + sg) = *(const ushort8*)(Al + aoff + k0);
    *(ushort8*)(sBh + sr*40 + sg) = *(const ushort8*)(Bh + boff + k0);
    *(ushort8*)(sBl + sr*40 + sg) = *(const ushort8*)(Bl + boff + k0);
    __syncthreads();
    short8 ah[4], al[4];
    #pragma unroll
    for (int m = 0; m < 4; ++m) {
      int r = m*16 + l15;
      ah[m] = *(const short8*)(sAh + r*40 + lhi*8);
      al[m] = *(const short8*)(sAl + r*40 + lhi*8);
    }
    int rb = wave*16 + l15;
    short8 bh = *(const short8*)(sBh + rb*40 + lhi*8);
    short8 bl = *(const short8*)(sBl + rb*40 + lhi*8);
    #pragma unroll
    for (int m = 0; m < 4; ++m) {
      acc[m] = MFMA(ah[m], bh, acc[m]);
      acc[m] = MFMA(al[m], bh, acc[m]);
      acc[m] = MFMA(ah[m], bl, acc[m]);
    }
  }

  int u = bn + wave*16 + l15;
  float bv = bias[u];
  int c  = u >> 2;
  int py = (u >> 1) & 1, px = u & 1;
  #pragma unroll
  for (int m = 0; m < 4; ++m) {
    int gr0 = bm + m*16 + lhi*4;
    #pragma unroll
    for (int r = 0; r < 4; ++r) {
      int t = gr0 + r;
      int y = (t >> 5)*2 + py, x = (t & 31)*2 + px;
      float v = acc[m][r] + bv;
      ushort hh, ll; split2(v, hh, ll);
      size_t o = (size_t)(y*64 + x)*256 + c;
      pH[o] = hh; pL[o] = ll;
    }
  }
}

// ---------------------------------------------------------------------------
// qkv GEMM + fused RMSNORM on A + RoPE + split -> Qs/Ks/Vt
// ---------------------------------------------------------------------------
__global__ __launch_bounds__(256,2)
void k_qkvrope(const float* __restrict__ tok, const float* __restrict__ nw,
               const ushort* __restrict__ Bh, const ushort* __restrict__ Bl,
               ushort* __restrict__ QsH, ushort* __restrict__ QsL,
               ushort* __restrict__ KsH, ushort* __restrict__ KsL,
               ushort* __restrict__ VtH, ushort* __restrict__ VtL) {
  __shared__ ushort sAh[64*40], sAl[64*40], sBh[64*40], sBl[64*40];
  __shared__ float sp[64][4];
  __shared__ float snorm[64];
  __shared__ float swt[256];
  int tid = threadIdx.x;
  int wave = tid >> 6, lane = tid & 63, l15 = lane & 15, lhi = lane >> 4;
  int bm = blockIdx.y * 64, bn = blockIdx.x * 64;
  int sr = tid >> 2, sg = (tid & 3) * 8;
  const int K = 256;
  const size_t boff = (size_t)(bn + sr) * K + sg;

  swt[tid] = nw[tid];
  {
    int r = tid >> 2, p = tid & 3;
    const float* row = tok + (size_t)(bm + r)*256 + p*64;
    float s = 0.f;
    for (int j = 0; j < 64; j += 4) {
      f32x4 v = *(const f32x4*)(row + j);
      s += v[0]*v[0] + v[1]*v[1] + v[2]*v[2] + v[3]*v[3];
    }
    sp[r][p] = s;
  }
  __syncthreads();
  if (tid < 64)
    snorm[tid] = rsqrtf((sp[tid][0]+sp[tid][1]+sp[tid][2]+sp[tid][3]) * (1.0f/256.0f) + 1e-6f);

  f32x4 acc[4];
  #pragma unroll
  for (int m = 0; m < 4; ++m) acc[m] = (f32x4){0.f,0.f,0.f,0.f};

  for (int k0 = 0; k0 < K; k0 += 32) {
    __syncthreads();
    {
      float nrm = snorm[sr];
      const float* src = tok + (size_t)(bm + sr)*256 + k0 + sg;
      ushort8 vh, vl;
      #pragma unroll
      for (int j = 0; j < 8; ++j) {
        float v = src[j] * nrm * swt[k0 + sg + j];
        ushort hh, ll; split2(v, hh, ll);
        vh[j] = hh; vl[j] = ll;
      }
      *(ushort8*)(sAh + sr*40 + sg) = vh;
      *(ushort8*)(sAl + sr*40 + sg) = vl;
    }
    *(ushort8*)(sBh + sr*40 + sg) = *(const ushort8*)(Bh + boff + k0);
    *(ushort8*)(sBl + sr*40 + sg) = *(const ushort8*)(Bl + boff + k0);
    __syncthreads();
    short8 ah[4], al[4];
    #pragma unroll
    for (int m = 0; m < 4; ++m) {
      int r = m*16 + l15;
      ah[m] = *(const short8*)(sAh + r*40 + lhi*8);
      al[m] = *(const short8*)(sAl + r*40 + lhi*8);
    }
    int rb = wave*16 + l15;
    short8 bh = *(const short8*)(sBh + rb*40 + lhi*8);
    short8 bl = *(const short8*)(sBl + rb*40 + lhi*8);
    #pragma unroll
    for (int m = 0; m < 4; ++m) {
      acc[m] = MFMA(ah[m], bh, acc[m]);
      acc[m] = MFMA(al[m], bh, acc[m]);
      acc[m] = MFMA(ah[m], bl, acc[m]);
    }
  }

  int gc = bn + wave*16 + l15;
  if (gc < 512) {
    int qk = gc >> 8;
    int c  = gc & 255;
    int h  = c >> 5, d = c & 31;
    int half = d >> 4, dd = d & 15, pd = dd >> 1, odd = dd & 1;
    float inv = powf(10.0f, -0.5f * (float)pd);
    float scl = qk ? 1.0f : 0.17677669529663687f;
    ushort* dH = qk ? KsH : QsH;
    ushort* dL = qk ? KsL : QsL;
    #pragma unroll
    for (int m = 0; m < 4; ++m) {
      int gr0 = bm + m*16 + lhi*4;
      #pragma unroll
      for (int r = 0; r < 4; ++r) {
        int t = gr0 + r;
        float v = acc[m][r];
        float pv = __shfl_xor(v, 1);
        float pos = (float)(half ? (t >> 5) : (t & 31));
        float ang = pos * inv;
        float cs = __cosf(ang), sn = __sinf(ang);
        float res = odd ? (pv*sn + v*cs) : (v*cs - pv*sn);
        res *= scl;
        ushort hh, ll; split2(res, hh, ll);
        size_t o = (size_t)h*32768 + (size_t)t*32 + d;
        dH[o] = hh; dL[o] = ll;
      }
    }
  } else {
    int c = gc - 512;
    int h = c >> 5, d = c & 31;
    #pragma unroll
    for (int m = 0; m < 4; ++m) {
      int t0 = bm + m*16 + lhi*4;
      ushort4v vh, vl;
      #pragma unroll
      for (int r = 0; r < 4; ++r) {
        ushort hh, ll; split2(acc[m][r], hh, ll);
        vh[r] = hh; vl[r] = ll;
      }
      size_t o = (size_t)h*32768 + (size_t)d*1024 + t0;
      *(ushort4v*)(VtH + o) = vh;
      *(ushort4v*)(VtL + o) = vl;
    }
  }
}

// ---------------------------------------------------------------------------
// Flash attention: block=(h,qt), 8 waves x 4 K-tiles, LDS merge.
// launch_bounds(512,4): 2 blocks/CU for cross-block latency hiding.
// ---------------------------------------------------------------------------
__global__ __launch_bounds__(512,4)
void k_fattn(const ushort* __restrict__ QsH, const ushort* __restrict__ QsL,
             const ushort* __restrict__ KsH, const ushort* __restrict__ KsL,
             const ushort* __restrict__ VtH, const ushort* __restrict__ VtL,
             ushort* __restrict__ oH, ushort* __restrict__ oL) {
  __shared__ float sM[8][64], sL[8][64];
  __shared__ float sO[8][64][16];
  int h  = blockIdx.x >> 5;
  int qt = blockIdx.x & 31;
  int tid = threadIdx.x;
  int wv = tid >> 6, lane = tid & 63;
  int l31 = lane & 31, lhi = (lane >> 5) & 1;

  const size_t qoff = ((size_t)h*1024 + qt*32 + l31)*32 + lhi*8;
  short8 qh = *(const short8*)(QsH + qoff);
  short8 ql = *(const short8*)(QsL + qoff);

  f32x16 oacc;
  #pragma unroll
  for (int r = 0; r < 16; ++r) oacc[r] = 0.f;
  float mrun = -INFINITY, lrun = 0.f;

  for (int kt = wv*4; kt < wv*4 + 4; ++kt) {
    const size_t koff = ((size_t)h*1024 + kt*32 + l31)*32 + lhi*8;
    short8 kh = *(const short8*)(KsH + koff);
    short8 kl = *(const short8*)(KsL + koff);
    const size_t voff = ((size_t)h*32 + l31)*1024 + kt*32 + lhi*8;
    short8 vh0 = *(const short8*)(VtH + voff);
    short8 vl0 = *(const short8*)(VtL + voff);
    short8 vh1 = *(const short8*)(VtH + voff + 16);
    short8 vl1 = *(const short8*)(VtL + voff + 16);

    f32x16 s;
    #pragma unroll
    for (int r = 0; r < 16; ++r) s[r] = 0.f;
    s = MFMA32(kh, qh, s);
    s = MFMA32(kl, qh, s);
    s = MFMA32(kh, ql, s);

    float mloc = s[0];
    #pragma unroll
    for (int r = 1; r < 16; ++r) mloc = fmaxf(mloc, s[r]);
    mloc = fmaxf(mloc, __shfl_xor(mloc, 32));
    float mnew = fmaxf(mrun, mloc);
    float fsc = __expf(mrun - mnew);
    float p[16]; float ssum = 0.f;
    #pragma unroll
    for (int r = 0; r < 16; ++r) { p[r] = __expf(s[r] - mnew); ssum += p[r]; }
    ssum += __shfl_xor(ssum, 32);
    lrun = lrun * fsc + ssum;
    mrun = mnew;
    #pragma unroll
    for (int r = 0; r < 16; ++r) oacc[r] *= fsc;

    unsigned wh[8], wl[8];
    #pragma unroll
    for (int i = 0; i < 8; ++i) {
      ushort h0,l0,h1,l1;
      split2(p[2*i], h0, l0);
      split2(p[2*i+1], h1, l1);
      wh[i] = (unsigned)h0 | ((unsigned)h1 << 16);
      wl[i] = (unsigned)l0 | ((unsigned)l1 << 16);
    }
    unsigned pwh[8], pwl[8];
    #pragma unroll
    for (int i = 0; i < 8; ++i) {
      pwh[i] = (unsigned)__shfl_xor((int)wh[i], 32);
      pwl[i] = (unsigned)__shfl_xor((int)wl[i], 32);
    }
    union U { unsigned u[4]; short8 s; };
    U bh0, bl0, bh1, bl1;
    bh0.u[0] = lhi ? pwh[2] : wh[0];  bh0.u[1] = lhi ? pwh[3] : wh[1];
    bh0.u[2] = lhi ? wh[2]  : pwh[0]; bh0.u[3] = lhi ? wh[3]  : pwh[1];
    bl0.u[0] = lhi ? pwl[2] : wl[0];  bl0.u[1] = lhi ? pwl[3] : wl[1];
    bl0.u[2] = lhi ? wl[2]  : pwl[0]; bl0.u[3] = lhi ? wl[3]  : pwl[1];
    bh1.u[0] = lhi ? pwh[6] : wh[4];  bh1.u[1] = lhi ? pwh[7] : wh[5];
    bh1.u[2] = lhi ? wh[6]  : pwh[4]; bh1.u[3] = lhi ? wh[7]  : pwh[5];
    bl1.u[0] = lhi ? pwl[6] : wl[4];  bl1.u[1] = lhi ? pwl[7] : wl[5];
    bl1.u[2] = lhi ? wl[6]  : pwl[4]; bl1.u[3] = lhi ? wl[7]  : pwl[5];

    oacc = MFMA32(vh0, bh0.s, oacc);
    oacc = MFMA32(vl0, bh0.s, oacc);
    oacc = MFMA32(vh0, bl0.s, oacc);
    oacc = MFMA32(vh1, bh1.s, oacc);
    oacc = MFMA32(vl1, bh1.s, oacc);
    oacc = MFMA32(vh1, bl1.s, oacc);
  }

  sM[wv][lane] = mrun;
  sL[wv][lane] = lrun;
  #pragma unroll
  for (int r = 0; r < 16; ++r) sO[wv][lane][r] = oacc[r];
  __syncthreads();

  if (wv == 0) {
    float M = sM[0][lane];
    #pragma unroll
    for (int w = 1; w < 8; ++w) M = fmaxf(M, sM[w][lane]);
    float L = 0.f;
    float O[16];
    #pragma unroll
    for (int r = 0; r < 16; ++r) O[r] = 0.f;
    #pragma unroll
    for (int w = 0; w < 8; ++w) {
      float f = __expf(sM[w][lane] - M);
      L += sL[w][lane] * f;
      #pragma unroll
      for (int r = 0; r < 16; ++r) O[r] += sO[w][lane][r] * f;
    }
    float inv = 1.0f / L;
    int t = qt*32 + l31;
    #pragma unroll
    for (int r = 0; r < 16; ++r) {
      int d = (r & 3) + 8*(r >> 2) + 4*lhi;
      float v = O[r] * inv;
      ushort hh, ll; split2(v, hh, ll);
      oH[(size_t)t*DIMD + h*32 + d] = hh;
      oL[(size_t)t*DIMD + h*32 + d] = ll;
    }
  }
}

// ---------------------------------------------------------------------------
// Fused gate/value GEMM + SiLU, with fused RMSNORM on A
// ---------------------------------------------------------------------------
__global__ __launch_bounds__(256,2)
void k_ffgv(const float* __restrict__ tok, const float* __restrict__ nw,
            const ushort* __restrict__ Bh, const ushort* __restrict__ Bl,
            ushort* __restrict__ fH, ushort* __restrict__ fL) {
  __shared__ ushort sAh[64*40], sAl[64*40];
  __shared__ ushort sGh[64*40], sGl[64*40];
  __shared__ ushort sVh[64*40], sVl[64*40];
  __shared__ float sp[64][4];
  __shared__ float snorm[64];
  __shared__ float swt[256];
  int tid = threadIdx.x;
  int wave = tid >> 6, lane = tid & 63, l15 = lane & 15, lhi = lane >> 4;
  int bm = blockIdx.y * 64, bn = blockIdx.x * 64;
  int sr = tid >> 2, sg = (tid & 3) * 8;
  const size_t goff = (size_t)(bn + sr) * 256 + sg;
  const size_t voff = (size_t)(1024 + bn + sr) * 256 + sg;

  swt[tid] = nw[tid];
  {
    int r = tid >> 2, p = tid & 3;
    const float* row = tok + (size_t)(bm + r)*256 + p*64;
    float s = 0.f;
    for (int j = 0; j < 64; j += 4) {
      f32x4 v = *(const f32x4*)(row + j);
      s += v[0]*v[0] + v[1]*v[1] + v[2]*v[2] + v[3]*v[3];
    }
    sp[r][p] = s;
  }
  __syncthreads();
  if (tid < 64)
    snorm[tid] = rsqrtf((sp[tid][0]+sp[tid][1]+sp[tid][2]+sp[tid][3]) * (1.0f/256.0f) + 1e-6f);

  f32x4 accg[4], accv[4];
  #pragma unroll
  for (int m = 0; m < 4; ++m) { accg[m] = (f32x4){0.f,0.f,0.f,0.f}; accv[m] = accg[m]; }

  for (int k0 = 0; k0 < 256; k0 += 32) {
    __syncthreads();
    {
      float nrm = snorm[sr];
      const float* src = tok + (size_t)(bm + sr)*256 + k0 + sg;
      ushort8 vh, vl;
      #pragma unroll
      for (int j = 0; j < 8; ++j) {
        float v = src[j] * nrm * swt[k0 + sg + j];
        ushort hh, ll; split2(v, hh, ll);
        vh[j] = hh; vl[j] = ll;
      }
      *(ushort8*)(sAh + sr*40 + sg) = vh;
      *(ushort8*)(sAl + sr*40 + sg) = vl;
    }
    *(ushort8*)(sGh + sr*40 + sg) = *(const ushort8*)(Bh + goff + k0);
    *(ushort8*)(sGl + sr*40 + sg) = *(const ushort8*)(Bl + goff + k0);
    *(ushort8*)(sVh + sr*40 + sg) = *(const ushort8*)(Bh + voff + k0);
    *(ushort8*)(sVl + sr*40 + sg) = *(const ushort8*)(Bl + voff + k0);
    __syncthreads();
    short8 ah[4], al[4];
    #pragma unroll
    for (int m = 0; m < 4; ++m) {
      int r = m*16 + l15;
      ah[m] = *(const short8*)(sAh + r*40 + lhi*8);
      al[m] = *(const short8*)(sAl + r*40 + lhi*8);
    }
    int rb = wave*16 + l15;
    short8 gh = *(const short8*)(sGh + rb*40 + lhi*8);
    short8 gl = *(const short8*)(sGl + rb*40 + lhi*8);
    short8 vh = *(const short8*)(sVh + rb*40 + lhi*8);
    short8 vl = *(const short8*)(sVl + rb*40 + lhi*8);
    #pragma unroll
    for (int m = 0; m < 4; ++m) {
      accg[m] = MFMA(ah[m], gh, accg[m]);
      accg[m] = MFMA(al[m], gh, accg[m]);
      accg[m] = MFMA(ah[m], gl, accg[m]);
      accv[m] = MFMA(ah[m], vh, accv[m]);
      accv[m] = MFMA(al[m], vh, accv[m]);
      accv[m] = MFMA(ah[m], vl, accv[m]);
    }
  }

  int gc = bn + wave*16 + l15;
  #pragma unroll
  for (int m = 0; m < 4; ++m) {
    int gr0 = bm + m*16 + lhi*4;
    #pragma unroll
    for (int r = 0; r < 4; ++r) {
      float g = accg[m][r], v = accv[m][r];
      float s = g / (1.0f + expf(-g));
      float rr = s * v;
      ushort hh, ll; split2(rr, hh, ll);
      size_t idx = (size_t)(gr0 + r)*1024 + gc;
      fH[idx] = hh; fL[idx] = ll;
    }
  }
}

// ---------------------------------------------------------------------------
// Fused query head: 512 threads / 8 waves. Activations hi-only (pin/h1/h2),
// weights stay split (2-term MFMAs). LDS ~26.5KB; launch_bounds(512,5).
// ---------------------------------------------------------------------------
#define H1S 260   // sH1 row stride (ushorts): 520B = 130 dwords, 130%32=2 -> conflict-free
__global__ __launch_bounds__(512,5)
void k_qhead(const float* __restrict__ qpos, const float* __restrict__ quinf,
             const float* __restrict__ qsdf, const float* __restrict__ qgrad,
             const float* __restrict__ projCL,
             const ushort* __restrict__ pw1tH, const ushort* __restrict__ pw1tL,
             const float* __restrict__ pb1,
             const ushort* __restrict__ wcH, const ushort* __restrict__ wcL,
             const float* __restrict__ b2eff,
             const ushort* __restrict__ dw2tH, const ushort* __restrict__ dw2tL,
             const float* __restrict__ db2,
             float* __restrict__ out) {
  __shared__ ushort sPinH[QN*72];
  __shared__ ushort sH1H[QN*H1S];
  __shared__ float  sXY[QN][2];
  __shared__ int    sBidx[QN][4];
  __shared__ float  sBw[QN][4];
  __shared__ float  sRed[8][128];

  int tid = threadIdx.x;
  int w = tid >> 6, lane = tid & 63, l15 = lane & 15, lhi = lane >> 4;
  int q0 = blockIdx.x * QN;

  if (tid < QN) {
    int qg = q0 + tid;
    float x = qpos[(size_t)qg*2 + 0], y = qpos[(size_t)qg*2 + 1];
    float xn = fminf(fmaxf(2.0f*(x + 2.0f)/6.0f - 1.0f, -1.0f), 1.0f);
    float yn = fminf(fmaxf(2.0f*(y + 1.5f)/3.0f - 1.0f, -1.0f), 1.0f);
    sXY[tid][0] = xn; sXY[tid][1] = yn;
    float px = (xn + 1.0f) * 0.5f * 63.0f;
    float py = (yn + 1.0f) * 0.5f * 63.0f;
    float x0 = fminf(fmaxf(floorf(px), 0.f), 63.f);
    float y0 = fminf(fmaxf(floorf(py), 0.f), 63.f);
    float wx = px - x0, wy = py - y0;
    int x0i = (int)x0, y0i = (int)y0;
    int x1i = min(x0i + 1, 63), y1i = min(y0i + 1, 63);
    sBidx[tid][0] = (y0i*64 + x0i)*256;
    sBidx[tid][1] = (y0i*64 + x1i)*256;
    sBidx[tid][2] = (y1i*64 + x0i)*256;
    sBidx[tid][3] = (y1i*64 + x1i)*256;
    sBw[tid][0] = (1.f-wx)*(1.f-wy);
    sBw[tid][1] = wx*(1.f-wy);
    sBw[tid][2] = (1.f-wx)*wy;
    sBw[tid][3] = wx*wy;
  }
  __syncthreads();

  {
    int q = tid >> 4;
    int j0 = (tid & 15) * 4;
    int qg = q0 + q;
    float xn = sXY[q][0], yn = sXY[q][1];
    #pragma unroll
    for (int jj = 0; jj < 4; ++jj) {
      int j = j0 + jj;
      float v = 0.f;
      if (j == 0) v = xn;
      else if (j == 1) v = yn;
      else if (j < 42) {
        int z = j - 2;
        int coord = z / 20;
        int ww = z % 20;
        int isCos = ww / 10;
        int fi = ww % 10;
        float f = ldexpf(3.14159265358979323846f, fi);
        float a = (coord ? yn : xn) * f;
        v = isCos ? __cosf(a) : __sinf(a);
      }
      else if (j < 44) v = quinf[(size_t)qg*2 + (j-42)];
      else if (j == 44) v = qsdf[qg];
      else if (j < 47) v = qgrad[(size_t)qg*2 + (j-45)];
      sPinH[q*72 + j] = bf16of(v);
    }
  }
  __syncthreads();

  f32x4 acc[2][2];
  #pragma unroll
  for (int m = 0; m < 2; ++m)
    #pragma unroll
    for (int n = 0; n < 2; ++n) acc[m][n] = (f32x4){0.f,0.f,0.f,0.f};

  // phase 1: h1 = pin @ pw1t (K=64); pin hi-only, weights split (2 terms)
  #pragma unroll
  for (int ks = 0; ks < 2; ++ks) {
    short8 bh[2], bl[2];
    #pragma unroll
    for (int n = 0; n < 2; ++n) {
      int r = w*32 + n*16 + l15;
      bh[n] = *(const short8*)(pw1tH + r*64 + ks*32 + lhi*8);
      bl[n] = *(const short8*)(pw1tL + r*64 + ks*32 + lhi*8);
    }
    short8 ah[2];
    #pragma unroll
    for (int m = 0; m < 2; ++m) {
      int r = m*16 + l15;
      ah[m] = *(const short8*)(sPinH + r*72 + ks*32 + lhi*8);
    }
    #pragma unroll
    for (int m = 0; m < 2; ++m)
      #pragma unroll
      for (int n = 0; n < 2; ++n) {
        acc[m][n] = MFMA(ah[m], bh[n], acc[m][n]);
        acc[m][n] = MFMA(ah[m], bl[n], acc[m][n]);
      }
  }
  // h1 epilogue (hi-only)
  #pragma unroll
  for (int m = 0; m < 2; ++m) {
    #pragma unroll
    for (int n = 0; n < 2; ++n) {
      int col = w*32 + n*16 + l15;
      float bv = pb1[col];
      #pragma unroll
      for (int r = 0; r < 4; ++r) {
        int row = m*16 + lhi*4 + r;
        float v = fmaxf(acc[m][n][r] + bv, 0.f);
        sH1H[row*H1S + col] = bf16of(v);
      }
      acc[m][n] = (f32x4){0.f,0.f,0.f,0.f};
    }
  }
  __syncthreads();

  // phase 2: h1 @ Wcomb (K=256), B double-buffered from global; h1 hi-only
  short8 pbh[2], pbl[2];
  #pragma unroll
  for (int n = 0; n < 2; ++n) {
    int r = w*32 + n*16 + l15;
    pbh[n] = *(const short8*)(wcH + (size_t)r*256 + lhi*8);
    pbl[n] = *(const short8*)(wcL + (size_t)r*256 + lhi*8);
  }
  #pragma unroll
  for (int ks = 0; ks < 8; ++ks) {
    short8 bh[2], bl[2];
    #pragma unroll
    for (int n = 0; n < 2; ++n) { bh[n] = pbh[n]; bl[n] = pbl[n]; }
    if (ks < 7) {
      #pragma unroll
      for (int n = 0; n < 2; ++n) {
        int r = w*32 + n*16 + l15;
        pbh[n] = *(const short8*)(wcH + (size_t)r*256 + (ks+1)*32 + lhi*8);
        pbl[n] = *(const short8*)(wcL + (size_t)r*256 + (ks+1)*32 + lhi*8);
      }
    }
    short8 ah[2];
    #pragma unroll
    for (int m = 0; m < 2; ++m) {
      int r = m*16 + l15;
      ah[m] = *(const short8*)(sH1H + r*H1S + ks*32 + lhi*8);
    }
    #pragma unroll
    for (int m = 0; m < 2; ++m)
      #pragma unroll
      for (int n = 0; n < 2; ++n) {
        acc[m][n] = MFMA(ah[m], bh[n], acc[m][n]);
        acc[m][n] = MFMA(ah[m], bl[n], acc[m][n]);
      }
  }
  __syncthreads();  // all waves finished reading sH1 (phase-2 A)

  // h2 epilogue: bilinear (LDS metadata) + b2eff + relu -> sH1 hi-only
  #pragma unroll
  for (int m = 0; m < 2; ++m) {
    #pragma unroll
    for (int r = 0; r < 4; ++r) {
      int q = m*16 + lhi*4 + r;
      int   b0 = sBidx[q][0], b1 = sBidx[q][1], b2 = sBidx[q][2], b3 = sBidx[q][3];
      float w0 = sBw[q][0],  w1 = sBw[q][1],  w2 = sBw[q][2],  w3 = sBw[q][3];
      #pragma unroll
      for (int n = 0; n < 2; ++n) {
        int col = w*32 + n*16 + l15;
        float bil = w0*projCL[b0+col] + w1*projCL[b1+col] + w2*projCL[b2+col] + w3*projCL[b3+col];
        float v = fmaxf(acc[m][n][r] + b2eff[col] + bil, 0.f);
        sH1H[q*H1S + col] = bf16of(v);
      }
    }
  }
  __syncthreads();

  // GEMV via MFMA: wave w contracts k-slice [w*32, w*32+32); h2 hi-only
  {
    short8 ah2[2];
    #pragma unroll
    for (int m = 0; m < 2; ++m) {
      int r = m*16 + l15;
      ah2[m] = *(const short8*)(sH1H + r*H1S + w*32 + lhi*8);
    }
    short8 bh2 = *(const short8*)(dw2tH + (size_t)l15*256 + w*32 + lhi*8);
    short8 bl2 = *(const short8*)(dw2tL + (size_t)l15*256 + w*32 + lhi*8);
    f32x4 c[2];
    #pragma unroll
    for (int m = 0; m < 2; ++m) {
      c[m] = (f32x4){0.f,0.f,0.f,0.f};
      c[m] = MFMA(ah2[m], bh2, c[m]);
      c[m] = MFMA(ah2[m], bl2, c[m]);
    }
    if (l15 < 4) {
      #pragma unroll
      for (int m = 0; m < 2; ++m)
        #pragma unroll
        for (int r = 0; r < 4; ++r)
          sRed[w][(m*16 + lhi*4 + r)*4 + l15] = c[m][r];
    }
  }
  __syncthreads();

  if (tid < 128) {
    int q = tid >> 2, d = tid & 3;
    float a = db2[d];
    #pragma unroll
    for (int ww = 0; ww < 8; ++ww) a += sRed[ww][q*4 + d];
    out[(size_t)(q0 + q)*4 + d] = a;
  }
}

// ---------------------------------------------------------------------------
extern "C" void kernel_launch(void* const* d_in, const int* in_sizes, int n_in,
                              void* d_out, int out_size, void* d_ws, size_t ws_size,
                              hipStream_t stream) {
  (void)in_sizes; (void)n_in; (void)out_size; (void)ws_size;
  const float* points     = (const float*)d_in[0];
  const float* grd        = (const float*)d_in[1];
  const float* qpos       = (const float*)d_in[2];
  const float* quinf      = (const float*)d_in[3];
  const float* qsdf       = (const float*)d_in[4];
  const float* qgrad      = (const float*)d_in[5];
  const float* enc_w1     = (const float*)d_in[6];
  const float* enc_b1     = (const float*)d_in[7];
  const float* enc_w2     = (const float*)d_in[8];
  const float* enc_b2     = (const float*)d_in[9];
  const float* inproj_w   = (const float*)d_in[10];
  const float* inproj_b   = (const float*)d_in[11];
  const float* patch_w    = (const float*)d_in[12];
  const float* patch_b    = (const float*)d_in[13];
  const float* norm1_w    = (const float*)d_in[14];
  const float* qkv_w      = (const float*)d_in[15];
  const float* attnproj_w = (const float*)d_in[16];
  const float* norm2_w    = (const float*)d_in[17];
  const float* gate_w     = (const float*)d_in[18];
  const float* value_w    = (const float*)d_in[19];
  const float* ffnout_w   = (const float*)d_in[20];
  const float* unpatch_w  = (const float*)d_in[21];
  const float* unpatch_b  = (const float*)d_in[22];
  const float* pw1        = (const float*)d_in[23];
  const float* pb1        = (const float*)d_in[24];
  const float* pw2        = (const float*)d_in[25];
  const float* pb2        = (const float*)d_in[26];
  const float* dw1        = (const float*)d_in[27];
  const float* db1        = (const float*)d_in[28];
  const float* dw2        = (const float*)d_in[29];
  const float* db2        = (const float*)d_in[30];
  float* out = (float*)d_out;

  char* base = (char*)d_ws;
  size_t off = 0;
  auto alloc = [&](size_t bytes) -> void* {
    void* p = base + off; off += (bytes + 255) & ~(size_t)255; return p;
  };

  // ---- persistent small transposed weights
  ushort* inprojTH = (ushort*)alloc(32768*2);   ushort* inprojTL = (ushort*)alloc(32768*2);
  ushort* patchTH  = (ushort*)alloc(262144*2);  ushort* patchTL  = (ushort*)alloc(262144*2);
  ushort* upTH     = (ushort*)alloc(262144*2);  ushort* upTL     = (ushort*)alloc(262144*2);
  ushort* pw1TH    = (ushort*)alloc(16384*2);   ushort* pw1TL    = (ushort*)alloc(16384*2);
  ushort* wcTH     = (ushort*)alloc(65536*2);   ushort* wcTL     = (ushort*)alloc(65536*2);
  ushort* dw1aTH   = (ushort*)alloc(65536*2);   ushort* dw1aTL   = (ushort*)alloc(65536*2);
  ushort* dw2tH    = (ushort*)alloc(4096*2);    ushort* dw2tL    = (ushort*)alloc(4096*2);
  float*  Wcomb    = (float*)alloc(65536*4);
  float*  b2eff    = (float*)alloc(256*4);

  // ---- binning
  int*   cellcnt   = (int*)alloc(NCELL*4);
  int*   cellstart = (int*)alloc((NCELL+1)*4);
  int*   cursor    = (int*)alloc(NCELL*4);
  float* bpx       = (float*)alloc(NPTS*4);
  float* bpy       = (float*)alloc(NPTS*4);
  int*   bpi       = (int*)alloc(NPTS*4);

  // ---- ALL transformer-layer weights (split once)
  ushort* lwH = (ushort*)alloc((size_t)NLAY*1048576*2);
  ushort* lwL = (ushort*)alloc((size_t)NLAY*1048576*2);
  const size_t qkvO = 0, apO = 196608, gateO = 262144, foO = 786432;

  // ---- activations
  ushort* featcH = (ushort*)alloc(524288*2);   ushort* featcL = (ushort*)alloc(524288*2);
  ushort* xpH = (ushort*)alloc(1048576*2);     // xp / ff / pr
  ushort* xpL = (ushort*)alloc(1048576*2);
  float*  tok = (float*)alloc(262144*4);
  ushort* tkH = (ushort*)alloc(262144*2);
  ushort* tkL = (ushort*)alloc(262144*2);
  ushort* oH  = (ushort*)alloc(262144*2);
  ushort* oL  = (ushort*)alloc(262144*2);
  float*  unionBuf = (float*)alloc(2097152*4); // Qs..Vt planes / projCL
  float*  projCL = unionBuf + 1048576;

  ushort* QsH = (ushort*)unionBuf;
  ushort* QsL = QsH + 262144;
  ushort* KsH = QsH + 2*262144;
  ushort* KsL = QsH + 3*262144;
  ushort* VtH = QsH + 4*262144;
  ushort* VtL = QsH + 5*262144;

  ushort* ffH = xpH;  ushort* ffL = xpL;
  ushort* prH = xpH;  ushort* prL = xpL;

  // ---- prep
  k_gemm<<<dim3(8,8), 256, 0, stream>>>(pw2, dw1 + 256*256, Wcomb, 256, 256, 512);
  k_beff<<<8, 256, 0, stream>>>(db1, pb2, dw1, b2eff);
  k_dw2t<<<1, 256, 0, stream>>>(dw2, dw2tH, dw2tL);

  auto addw = [](STable& t, int& cb, const float* src, ushort* dh, ushort* dl,
                 int K, int N, int Kp) {
    SDesc& s = t.d[t.nw]; s.src = src; s.dh = dh; s.dl = dl;
    s.K = K; s.N = N; s.Kp = Kp; s.blk0 = cb;
    cb += (Kp >> 5) * (N >> 5); t.nw++;
  };

  {
    STable gt; gt.nw = 0; int cb = 0;
    addw(gt, cb, inproj_w, inprojTH, inprojTL, 128, 256, 128);
    addw(gt, cb, patch_w,  patchTH,  patchTL,  1024, 256, 1024);
    addw(gt, cb, unpatch_w, upTH, upTL, 256, 1024, 256);
    addw(gt, cb, pw1,   pw1TH,  pw1TL,  47, 256, 64);
    addw(gt, cb, Wcomb, wcTH,   wcTL,   256, 256, 256);
    addw(gt, cb, dw1,   dw1aTH, dw1aTL, 256, 256, 256);
    for (int l = 0; l < NLAY; ++l) {
      size_t lb = (size_t)l*1048576;
      addw(gt, cb, qkv_w      + (size_t)l*196608, lwH + lb + qkvO,  lwL + lb + qkvO,  256, 768, 256);
      addw(gt, cb, attnproj_w + (size_t)l*65536,  lwH + lb + apO,   lwL + lb + apO,   256, 256, 256);
      addw(gt, cb, gate_w     + (size_t)l*262144, lwH + lb + gateO,          lwL + lb + gateO,          256, 1024, 256);
      addw(gt, cb, value_w    + (size_t)l*262144, lwH + lb + gateO + 262144, lwL + lb + gateO + 262144, 256, 1024, 256);
      addw(gt, cb, ffnout_w   + (size_t)l*262144, lwH + lb + foO,   lwL + lb + foO,   1024, 256, 1024);
    }
    k_splitT_all<<<cb, 256, 0, stream>>>(gt);
  }

  k_zero<<<4, 256, 0, stream>>>(cellcnt);
  k_bincount<<<(NPTS+255)/256, 256, 0, stream>>>(points, cellcnt);
  k_prefix<<<1, 1024, 0, stream>>>(cellcnt, cellstart, cursor);
  k_scatter<<<(NPTS+255)/256, 256, 0, stream>>>(points, cursor, bpx, bpy, bpi);

  // ---- encode + patchify
  k_encode<<<dim3(GRD, 2), 256, 0, stream>>>(bpx, bpy, bpi, cellstart, grd,
                                             enc_w1, enc_b1, enc_w2, enc_b2, featcH, featcL);
  k_inproj<<<dim3(4,64), 256, 0, stream>>>(featcH, featcL, inprojTH, inprojTL, inproj_b, xpH, xpL);
  k_mgemm64<true,false,false,2><<<dim3(4,32), 256, 0, stream>>>(xpH, xpL, patchTH, patchTL, patch_b, nullptr, tok, TOK, 256, 1024, nullptr, nullptr);

  // ---- transformer
  for (int l = 0; l < NLAY; ++l) {
    size_t lb = (size_t)l*1048576;
    k_qkvrope<<<dim3(12,16), 256, 0, stream>>>(tok, norm1_w + (size_t)l*DIMD,
                                               lwH + lb + qkvO, lwL + lb + qkvO,
                                               QsH, QsL, KsH, KsL, VtH, VtL);
    k_fattn<<<256, 512, 0, stream>>>(QsH, QsL, KsH, KsL, VtH, VtL, oH, oL);
    k_mgemm64<false,true,false,2><<<dim3(4,32), 256, 0, stream>>>(oH, oL, lwH + lb + apO, lwL + lb + apO, nullptr, tok, tok, TOK, 256, 256, nullptr, nullptr);
    k_ffgv<<<dim3(16,16), 256, 0, stream>>>(tok, norm2_w + (size_t)l*DIMD,
                                            lwH + lb + gateO, lwL + lb + gateO, ffH, ffL);
    if (l < NLAY-1)
      k_mgemm64<false,true,false,2><<<dim3(4,32), 256, 0, stream>>>(ffH, ffL, lwH + lb + foO, lwL + lb + foO, nullptr, tok, tok, TOK, 256, 1024, nullptr, nullptr);
    else
      k_mgemm64<false,true,true,2><<<dim3(4,32), 256, 0, stream>>>(ffH, ffL, lwH + lb + foO, lwL + lb + foO, nullptr, tok, tok, TOK, 256, 1024, tkH, tkL);
  }

  // ---- unpatch GEMM (fused permute) + grid projection
  k_upgemm<<<dim3(16,16), 256, 0, stream>>>(tkH, tkL, upTH, upTL, unpatch_b, prH, prL);
  k_mgemm64<false,false,false,4><<<dim3(4,64), 256, 0, stream>>>(prH, prL, dw1aTH, dw1aTL, nullptr, nullptr, projCL, GRD, 256, 256, nullptr, nullptr);

  // ---- query head
  k_qhead<<<NQ/QN, 512, 0, stream>>>(qpos, quinf, qsdf, qgrad, projCL,
      pw1TH, pw1TL, pb1, wcTH, wcTL, b2eff, dw2tH, dw2tL, db2, out);
}

// Round 11
// 676.516 us; speedup vs baseline: 1.0541x; 1.0541x over previous
//
#include <hip/hip_runtime.h>
#include <math.h>

typedef __attribute__((ext_vector_type(8))) short short8;
typedef __attribute__((ext_vector_type(8))) unsigned short ushort8;
typedef __attribute__((ext_vector_type(4))) unsigned short ushort4v;
typedef __attribute__((ext_vector_type(4))) float f32x4;
typedef __attribute__((ext_vector_type(16))) float f32x16;

#define NPTS  20000
#define NQ    100000
#define TOK   1024
#define DIMD  256
#define NHD   8
#define NLAY  5
#define GRD   4096
#define CAP   512
#define QN    32

#define XMINF (-2.0f)
#define YMINF (-1.5f)
#define CELL  0.15f
#define NCX   40
#define NCY   20
#define NCELL 800

#define MFMA(a,b,c)   __builtin_amdgcn_mfma_f32_16x16x32_bf16(a,b,c,0,0,0)
#define MFMA32(a,b,c) __builtin_amdgcn_mfma_f32_32x32x16_bf16(a,b,c,0,0,0)

__device__ inline void split2(float x, ushort& h, ushort& l) {
  unsigned u = __float_as_uint(x);
  unsigned hr = (u + 0x7FFFu + ((u >> 16) & 1u)) & 0xFFFF0000u;
  h = (ushort)(hr >> 16);
  float r = x - __uint_as_float(hr);
  unsigned u2 = __float_as_uint(r);
  l = (ushort)((u2 + 0x7FFFu + ((u2 >> 16) & 1u)) >> 16);
}

// ---------------------------------------------------------------------------
// Point binning
// ---------------------------------------------------------------------------
__device__ inline int cell_of(float px, float py) {
  int cx = (int)floorf((px - XMINF) / CELL);
  int cy = (int)floorf((py - YMINF) / CELL);
  cx = min(max(cx, 0), NCX - 1);
  cy = min(max(cy, 0), NCY - 1);
  return cy * NCX + cx;
}

__global__ void k_zero(int* __restrict__ cnt) {
  int i = blockIdx.x * 256 + threadIdx.x;
  if (i < NCELL) cnt[i] = 0;
}

__global__ void k_bincount(const float* __restrict__ pts, int* __restrict__ cnt) {
  int p = blockIdx.x * 256 + threadIdx.x;
  if (p < NPTS) atomicAdd(&cnt[cell_of(pts[p*2], pts[p*2+1])], 1);
}

__global__ void k_prefix(const int* __restrict__ cnt, int* __restrict__ start,
                         int* __restrict__ cursor) {
  __shared__ int s[1024];
  int t = threadIdx.x;
  int v0 = (t < NCELL) ? cnt[t] : 0;
  s[t] = v0;
  __syncthreads();
  for (int off = 1; off < 1024; off <<= 1) {
    int v = (t >= off) ? s[t - off] : 0;
    __syncthreads();
    s[t] += v;
    __syncthreads();
  }
  int ex = s[t] - v0;
  if (t < NCELL) { start[t] = ex; cursor[t] = ex; }
  if (t == 0) start[NCELL] = NPTS;
}

__global__ void k_scatter(const float* __restrict__ pts, int* __restrict__ cursor,
                          float* __restrict__ bpx, float* __restrict__ bpy,
                          int* __restrict__ bpi) {
  int p = blockIdx.x * 256 + threadIdx.x;
  if (p < NPTS) {
    float px = pts[p*2], py = pts[p*2+1];
    int slot = atomicAdd(&cursor[cell_of(px, py)], 1);
    bpx[slot] = px; bpy[slot] = py; bpi[slot] = p;
  }
}

// ---------------------------------------------------------------------------
// Encode
// ---------------------------------------------------------------------------
__global__ void k_encode(const float* __restrict__ bpx, const float* __restrict__ bpy,
                         const int* __restrict__ bpi, const int* __restrict__ cellstart,
                         const float* __restrict__ grd,
                         const float* __restrict__ w1, const float* __restrict__ b1,
                         const float* __restrict__ w2, const float* __restrict__ b2,
                         ushort* __restrict__ fH, ushort* __restrict__ fL) {
  __shared__ float s_d2[CAP], s_px[CAP], s_py[CAP];
  __shared__ int   s_idx[CAP];
  __shared__ int   s_cnt;
  __shared__ float s_selx[32], s_sely[32];
  __shared__ float s_part[4][64];

  int gi = blockIdx.x, sc = blockIdx.y;
  int tid = threadIdx.x;
  const float radius = (sc == 0) ? 0.15f : 0.30f;
  const int   K      = (sc == 0) ? 16 : 32;
  float gx = grd[gi*2+0], gy = grd[gi*2+1];
  float g2 = __fadd_rn(__fmul_rn(gx,gx), __fmul_rn(gy,gy));
  float r2 = __fmul_rn(radius, radius);

  if (tid == 0) s_cnt = 0;
  __syncthreads();

  int cx0 = min(max((int)floorf((gx - radius - XMINF) / CELL), 0), NCX - 1);
  int cx1 = min(max((int)floorf((gx + radius - XMINF) / CELL), 0), NCX - 1);
  int cy0 = min(max((int)floorf((gy - radius - YMINF) / CELL), 0), NCY - 1);
  int cy1 = min(max((int)floorf((gy + radius - YMINF) / CELL), 0), NCY - 1);

  for (int cy = cy0; cy <= cy1; ++cy) {
    int b0 = cellstart[cy*NCX + cx0];
    int b1 = cellstart[cy*NCX + cx1 + 1];
    for (int i = b0 + tid; i < b1; i += 256) {
      float px = bpx[i], py = bpy[i];
      float p2  = __fadd_rn(__fmul_rn(px,px), __fmul_rn(py,py));
      float dot = __fadd_rn(__fmul_rn(gx,px), __fmul_rn(gy,py));
      float d2  = __fsub_rn(__fadd_rn(g2,p2), __fmul_rn(2.0f,dot));
      if (d2 < r2) {
        int pos = atomicAdd(&s_cnt, 1);
        if (pos < CAP) { s_d2[pos] = d2; s_px[pos] = px; s_py[pos] = py; s_idx[pos] = bpi[i]; }
      }
    }
  }
  __syncthreads();
  int m = min(s_cnt, CAP);
  int nsel;

  if (m > K) {
    for (int i = tid; i < m; i += 256) {
      float di = s_d2[i];
      int   pi = s_idx[i];
      int rank = 0;
      for (int j = 0; j < m; ++j) {
        float dj = s_d2[j];
        rank += (dj < di || (dj == di && s_idx[j] < pi)) ? 1 : 0;
      }
      if (rank < K) { s_selx[rank] = s_px[i]; s_sely[rank] = s_py[i]; }
    }
    nsel = K;
  } else {
    if (tid < m) { s_selx[tid] = s_px[tid]; s_sely[tid] = s_py[tid]; }
    nsel = m;
  }
  __syncthreads();

  int grp = tid >> 6, d = tid & 63;
  s_part[grp][d] = -INFINITY;
  __syncthreads();
  const float* W1 = w1 + sc*64;
  const float* B1 = b1 + sc*32;
  const float* W2 = w2 + sc*2048;
  const float* B2 = b2 + sc*64;
  for (int base = 0; base < nsel; base += 4) {
    int pi = base + grp;
    if (pi < nsel) {
      float rx = s_selx[pi] - gx;
      float ry = s_sely[pi] - gy;
      float f = B2[d];
      #pragma unroll
      for (int j = 0; j < 32; ++j) {
        float h = rx * W1[j] + ry * W1[32 + j] + B1[j];
        h = fmaxf(h, 0.0f);
        f += h * W2[j*64 + d];
      }
      s_part[grp][d] = fmaxf(s_part[grp][d], f);
    }
  }
  __syncthreads();
  if (tid < 64) {
    float v = fmaxf(fmaxf(s_part[0][tid], s_part[1][tid]),
                    fmaxf(s_part[2][tid], s_part[3][tid]));
    if (nsel == 0) v = 0.0f;
    ushort h, l; split2(v, h, l);
    fH[gi*128 + sc*64 + tid] = h;
    fL[gi*128 + sc*64 + tid] = l;
  }
}

// ---------------------------------------------------------------------------
// f32 tiled GEMM (Wcomb precompute only)
// ---------------------------------------------------------------------------
__global__ void k_gemm(const float* __restrict__ A, const float* __restrict__ B,
                       float* __restrict__ C, int M, int N, int K) {
  __shared__ float As[32][33];
  __shared__ float Bs[32][33];
  int bm = blockIdx.y * 32, bn = blockIdx.x * 32;
  int tx = threadIdx.x & 31, ty = threadIdx.x >> 5;
  float acc[4] = {0.f, 0.f, 0.f, 0.f};
  for (int k0 = 0; k0 < K; k0 += 32) {
    for (int i = threadIdx.x; i < 1024; i += 256) {
      int r = i >> 5, c = i & 31;
      As[r][c] = A[(size_t)(bm + r)*K + k0 + c];
      Bs[r][c] = B[(size_t)(k0 + r)*N + bn + c];
    }
    __syncthreads();
    #pragma unroll
    for (int kk = 0; kk < 32; ++kk) {
      float bv = Bs[kk][tx];
      #pragma unroll
      for (int i = 0; i < 4; ++i) acc[i] += As[ty + 8*i][kk] * bv;
    }
    __syncthreads();
  }
  #pragma unroll
  for (int i = 0; i < 4; ++i)
    C[(size_t)(bm + ty + 8*i)*N + bn + tx] = acc[i];
}

__global__ void k_beff(const float* __restrict__ db1, const float* __restrict__ pb2,
                       const float* __restrict__ dw1, float* __restrict__ b2eff) {
  __shared__ float red[8][32];
  int n0 = blockIdx.x * 32;
  int t = threadIdx.x;
  int nn = t & 31, jc = t >> 5;
  float a = 0.f;
  for (int j = jc*64; j < jc*64 + 64; ++j)
    a += pb2[j] * dw1[(size_t)(256 + j)*256 + n0 + nn];
  red[jc][nn] = a;
  __syncthreads();
  if (t < 32) {
    float s = db1[n0 + t];
    #pragma unroll
    for (int w = 0; w < 8; ++w) s += red[w][t];
    b2eff[n0 + t] = s;
  }
}

__global__ void k_dw2t(const float* __restrict__ dw2,
                       ushort* __restrict__ tH, ushort* __restrict__ tL) {
  int k = threadIdx.x;
  #pragma unroll
  for (int d = 0; d < 16; ++d) {
    float v = (d < 4) ? dw2[k*4 + d] : 0.f;
    ushort h, l; split2(v, h, l);
    tH[d*256 + k] = h; tL[d*256 + k] = l;
  }
}

// ---------------------------------------------------------------------------
// Split+transpose weights
// ---------------------------------------------------------------------------
struct SDesc { const float* src; ushort* dh; ushort* dl; int K, N, Kp, blk0; };
struct STable { int nw; SDesc d[31]; };

__global__ void k_splitT_all(STable tab) {
  __shared__ float tile[32][33];
  int b = blockIdx.x;
  int w = 0;
  for (int i = 1; i < tab.nw; ++i) if (b >= tab.d[i].blk0) w = i;
  SDesc s = tab.d[w];
  int rel = b - s.blk0;
  int ntn = s.N >> 5;
  int tk = rel / ntn, tn = rel - tk*ntn;
  int r = threadIdx.x >> 5, c = threadIdx.x & 31;
  #pragma unroll
  for (int i = 0; i < 4; ++i) {
    int kk = tk*32 + r + i*8;
    tile[r + i*8][c] = (kk < s.K) ? s.src[(size_t)kk*s.N + tn*32 + c] : 0.f;
  }
  __syncthreads();
  #pragma unroll
  for (int i = 0; i < 4; ++i) {
    int nn = tn*32 + r + i*8;
    float v = tile[c][r + i*8];
    ushort hh, ll; split2(v, hh, ll);
    size_t o = (size_t)nn*s.Kp + tk*32 + c;
    s.dh[o] = hh; s.dl[o] = ll;
  }
}

// ---------------------------------------------------------------------------
// Split-bf16 MFMA GEMM, tile (MT*16)x64. Optional split shadow write of C.
// ---------------------------------------------------------------------------
template<bool BIAS, bool RESID, bool WSPLIT, int MT>
__global__ __launch_bounds__(256,2)
void k_mgemm64(const ushort* __restrict__ Ah, const ushort* __restrict__ Al,
               const ushort* __restrict__ Bh, const ushort* __restrict__ Bl,
               const float* __restrict__ bias, const float* __restrict__ resid,
               float* __restrict__ C, int M, int N, int K,
               ushort* __restrict__ wsH, ushort* __restrict__ wsL) {
  __shared__ ushort sAh[MT*16*40], sAl[MT*16*40], sBh[64*40], sBl[64*40];
  int tid = threadIdx.x;
  int wave = tid >> 6, lane = tid & 63, l15 = lane & 15, lhi = lane >> 4;
  int bm = blockIdx.y * (MT*16), bn = blockIdx.x * 64;
  int sr = tid >> 2, sg = (tid & 3) * 8;
  const size_t boff = (size_t)(bn + sr) * K + sg;
  f32x4 acc[MT];
  #pragma unroll
  for (int m = 0; m < MT; ++m) acc[m] = (f32x4){0.f,0.f,0.f,0.f};

  for (int k0 = 0; k0 < K; k0 += 32) {
    __syncthreads();
    if (MT == 4) {
      const size_t aoff = (size_t)(bm + sr) * K + sg;
      *(ushort8*)(sAh + sr*40 + sg) = *(const ushort8*)(Ah + aoff + k0);
      *(ushort8*)(sAl + sr*40 + sg) = *(const ushort8*)(Al + aoff + k0);
    } else {
      int ar = (tid & 127) >> 2, ag = (tid & 3) * 8;
      const ushort* src = (tid < 128) ? Ah : Al;
      ushort* dst = (tid < 128) ? sAh : sAl;
      *(ushort8*)(dst + ar*40 + ag) = *(const ushort8*)(src + (size_t)(bm + ar)*K + k0 + ag);
    }
    *(ushort8*)(sBh + sr*40 + sg) = *(const ushort8*)(Bh + boff + k0);
    *(ushort8*)(sBl + sr*40 + sg) = *(const ushort8*)(Bl + boff + k0);
    __syncthreads();
    short8 ah[MT], al[MT];
    #pragma unroll
    for (int m = 0; m < MT; ++m) {
      int r = m*16 + l15;
      ah[m] = *(const short8*)(sAh + r*40 + lhi*8);
      al[m] = *(const short8*)(sAl + r*40 + lhi*8);
    }
    int rb = wave*16 + l15;
    short8 bh = *(const short8*)(sBh + rb*40 + lhi*8);
    short8 bl = *(const short8*)(sBl + rb*40 + lhi*8);
    #pragma unroll
    for (int m = 0; m < MT; ++m) {
      acc[m] = MFMA(ah[m], bh, acc[m]);
      acc[m] = MFMA(al[m], bh, acc[m]);
      acc[m] = MFMA(ah[m], bl, acc[m]);
    }
  }

  int gc = bn + wave*16 + l15;
  float bv = BIAS ? bias[gc] : 0.f;
  #pragma unroll
  for (int m = 0; m < MT; ++m) {
    int gr0 = bm + m*16 + lhi*4;
    #pragma unroll
    for (int r = 0; r < 4; ++r) {
      size_t idx = (size_t)(gr0 + r)*N + gc;
      float v = acc[m][r] + bv;
      if (RESID) v += resid[idx];
      C[idx] = v;
      if (WSPLIT) {
        ushort hh, ll; split2(v, hh, ll);
        wsH[idx] = hh; wsL[idx] = ll;
      }
    }
  }
}

// ---------------------------------------------------------------------------
// inproj GEMM with fused patch-gather epilogue -> xp split
// ---------------------------------------------------------------------------
__global__ __launch_bounds__(256,2)
void k_inproj(const ushort* __restrict__ Ah, const ushort* __restrict__ Al,
              const ushort* __restrict__ Bh, const ushort* __restrict__ Bl,
              const float* __restrict__ bias,
              ushort* __restrict__ xH, ushort* __restrict__ xL) {
  __shared__ ushort sAh[64*40], sAl[64*40], sBh[64*40], sBl[64*40];
  int tid = threadIdx.x;
  int wave = tid >> 6, lane = tid & 63, l15 = lane & 15, lhi = lane >> 4;
  int bm = blockIdx.y * 64, bn = blockIdx.x * 64;
  int sr = tid >> 2, sg = (tid & 3) * 8;
  const int K = 128;
  const size_t aoff = (size_t)(bm + sr) * K + sg;
  const size_t boff = (size_t)(bn + sr) * K + sg;
  f32x4 acc[4];
  #pragma unroll
  for (int m = 0; m < 4; ++m) acc[m] = (f32x4){0.f,0.f,0.f,0.f};

  for (int k0 = 0; k0 < K; k0 += 32) {
    __syncthreads();
    *(ushort8*)(sAh + sr*40 + sg) = *(const ushort8*)(Ah + aoff + k0);
    *(ushort8*)(sAl + sr*40 + sg) = *(const ushort8*)(Al + aoff + k0);
    *(ushort8*)(sBh + sr*40 + sg) = *(const ushort8*)(Bh + boff + k0);
    *(ushort8*)(sBl + sr*40 + sg) = *(const ushort8*)(Bl + boff + k0);
    __syncthreads();
    short8 ah[4], al[4];
    #pragma unroll
    for (int m = 0; m < 4; ++m) {
      int r = m*16 + l15;
      ah[m] = *(const short8*)(sAh + r*40 + lhi*8);
      al[m] = *(const short8*)(sAl + r*40 + lhi*8);
    }
    int rb = wave*16 + l15;
    short8 bh = *(const short8*)(sBh + rb*40 + lhi*8);
    short8 bl = *(const short8*)(sBl + rb*40 + lhi*8);
    #pragma unroll
    for (int m = 0; m < 4; ++m) {
      acc[m] = MFMA(ah[m], bh, acc[m]);
      acc[m] = MFMA(al[m], bh, acc[m]);
      acc[m] = MFMA(ah[m], bl, acc[m]);
    }
  }

  int gc = bn + wave*16 + l15;
  float bv = bias[gc];
  #pragma unroll
  for (int m = 0; m < 4; ++m) {
    int gr0 = bm + m*16 + lhi*4;
    #pragma unroll
    for (int r = 0; r < 4; ++r) {
      int g = gr0 + r;
      int y = g >> 6, x = g & 63;
      int t = (y >> 1)*32 + (x >> 1);
      int f = gc*4 + (y & 1)*2 + (x & 1);
      float v = acc[m][r] + bv;
      ushort hh, ll; split2(v, hh, ll);
      size_t o = (size_t)t*1024 + f;
      xH[o] = hh; xL[o] = ll;
    }
  }
}

// ---------------------------------------------------------------------------
// unpatch GEMM with fused unpatch epilogue -> pr split
// ---------------------------------------------------------------------------
__global__ __launch_bounds__(256,2)
void k_upgemm(const ushort* __restrict__ Ah, const ushort* __restrict__ Al,
              const ushort* __restrict__ Bh, const ushort* __restrict__ Bl,
              const float* __restrict__ bias,
              ushort* __restrict__ pH, ushort* __restrict__ pL) {
  __shared__ ushort sAh[64*40], sAl[64*40], sBh[64*40], sBl[64*40];
  int tid = threadIdx.x;
  int wave = tid >> 6, lane = tid & 63, l15 = lane & 15, lhi = lane >> 4;
  int bm = blockIdx.y * 64, bn = blockIdx.x * 64;
  int sr = tid >> 2, sg = (tid & 3) * 8;
  const int K = 256;
  const size_t aoff = (size_t)(bm + sr) * K + sg;
  const size_t boff = (size_t)(bn + sr) * K + sg;
  f32x4 acc[4];
  #pragma unroll
  for (int m = 0; m < 4; ++m) acc[m] = (f32x4){0.f,0.f,0.f,0.f};

  for (int k0 = 0; k0 < K; k0 += 32) {
    __syncthreads();
    *(ushort8*)(sAh + sr*40 + sg) = *(const ushort8*)(Ah + aoff + k0);
    *(ushort8*)(sAl + sr*40 + sg) = *(const ushort8*)(Al + aoff + k0);
    *(ushort8*)(sBh + sr*40 + sg) = *(const ushort8*)(Bh + boff + k0);
    *(ushort8*)(sBl + sr*40 + sg) = *(const ushort8*)(Bl + boff + k0);
    __syncthreads();
    short8 ah[4], al[4];
    #pragma unroll
    for (int m = 0; m < 4; ++m) {
      int r = m*16 + l15;
      ah[m] = *(const short8*)(sAh + r*40 + lhi*8);
      al[m] = *(const short8*)(sAl + r*40 + lhi*8);
    }
    int rb = wave*16 + l15;
    short8 bh = *(const short8*)(sBh + rb*40 + lhi*8);
    short8 bl = *(const short8*)(sBl + rb*40 + lhi*8);
    #pragma unroll
    for (int m = 0; m < 4; ++m) {
      acc[m] = MFMA(ah[m], bh, acc[m]);
      acc[m] = MFMA(al[m], bh, acc[m]);
      acc[m] = MFMA(ah[m], bl, acc[m]);
    }
  }

  int u = bn + wave*16 + l15;
  float bv = bias[u];
  int c  = u >> 2;
  int py = (u >> 1) & 1, px = u & 1;
  #pragma unroll
  for (int m = 0; m < 4; ++m) {
    int gr0 = bm + m*16 + lhi*4;
    #pragma unroll
    for (int r = 0; r < 4; ++r) {
      int t = gr0 + r;
      int y = (t >> 5)*2 + py, x = (t & 31)*2 + px;
      float v = acc[m][r] + bv;
      ushort hh, ll; split2(v, hh, ll);
      size_t o = (size_t)(y*64 + x)*256 + c;
      pH[o] = hh; pL[o] = ll;
    }
  }
}

// ---------------------------------------------------------------------------
// qkv GEMM + fused RMSNORM on A + RoPE + split -> Qs/Ks/Vt
// ---------------------------------------------------------------------------
__global__ __launch_bounds__(256,2)
void k_qkvrope(const float* __restrict__ tok, const float* __restrict__ nw,
               const ushort* __restrict__ Bh, const ushort* __restrict__ Bl,
               ushort* __restrict__ QsH, ushort* __restrict__ QsL,
               ushort* __restrict__ KsH, ushort* __restrict__ KsL,
               ushort* __restrict__ VtH, ushort* __restrict__ VtL) {
  __shared__ ushort sAh[64*40], sAl[64*40], sBh[64*40], sBl[64*40];
  __shared__ float sp[64][4];
  __shared__ float snorm[64];
  __shared__ float swt[256];
  int tid = threadIdx.x;
  int wave = tid >> 6, lane = tid & 63, l15 = lane & 15, lhi = lane >> 4;
  int bm = blockIdx.y * 64, bn = blockIdx.x * 64;
  int sr = tid >> 2, sg = (tid & 3) * 8;
  const int K = 256;
  const size_t boff = (size_t)(bn + sr) * K + sg;

  swt[tid] = nw[tid];
  {
    int r = tid >> 2, p = tid & 3;
    const float* row = tok + (size_t)(bm + r)*256 + p*64;
    float s = 0.f;
    for (int j = 0; j < 64; j += 4) {
      f32x4 v = *(const f32x4*)(row + j);
      s += v[0]*v[0] + v[1]*v[1] + v[2]*v[2] + v[3]*v[3];
    }
    sp[r][p] = s;
  }
  __syncthreads();
  if (tid < 64)
    snorm[tid] = rsqrtf((sp[tid][0]+sp[tid][1]+sp[tid][2]+sp[tid][3]) * (1.0f/256.0f) + 1e-6f);

  f32x4 acc[4];
  #pragma unroll
  for (int m = 0; m < 4; ++m) acc[m] = (f32x4){0.f,0.f,0.f,0.f};

  for (int k0 = 0; k0 < K; k0 += 32) {
    __syncthreads();
    {
      float nrm = snorm[sr];
      const float* src = tok + (size_t)(bm + sr)*256 + k0 + sg;
      ushort8 vh, vl;
      #pragma unroll
      for (int j = 0; j < 8; ++j) {
        float v = src[j] * nrm * swt[k0 + sg + j];
        ushort hh, ll; split2(v, hh, ll);
        vh[j] = hh; vl[j] = ll;
      }
      *(ushort8*)(sAh + sr*40 + sg) = vh;
      *(ushort8*)(sAl + sr*40 + sg) = vl;
    }
    *(ushort8*)(sBh + sr*40 + sg) = *(const ushort8*)(Bh + boff + k0);
    *(ushort8*)(sBl + sr*40 + sg) = *(const ushort8*)(Bl + boff + k0);
    __syncthreads();
    short8 ah[4], al[4];
    #pragma unroll
    for (int m = 0; m < 4; ++m) {
      int r = m*16 + l15;
      ah[m] = *(const short8*)(sAh + r*40 + lhi*8);
      al[m] = *(const short8*)(sAl + r*40 + lhi*8);
    }
    int rb = wave*16 + l15;
    short8 bh = *(const short8*)(sBh + rb*40 + lhi*8);
    short8 bl = *(const short8*)(sBl + rb*40 + lhi*8);
    #pragma unroll
    for (int m = 0; m < 4; ++m) {
      acc[m] = MFMA(ah[m], bh, acc[m]);
      acc[m] = MFMA(al[m], bh, acc[m]);
      acc[m] = MFMA(ah[m], bl, acc[m]);
    }
  }

  int gc = bn + wave*16 + l15;
  if (gc < 512) {
    int qk = gc >> 8;
    int c  = gc & 255;
    int h  = c >> 5, d = c & 31;
    int half = d >> 4, dd = d & 15, pd = dd >> 1, odd = dd & 1;
    float inv = powf(10.0f, -0.5f * (float)pd);
    float scl = qk ? 1.0f : 0.17677669529663687f;
    ushort* dH = qk ? KsH : QsH;
    ushort* dL = qk ? KsL : QsL;
    #pragma unroll
    for (int m = 0; m < 4; ++m) {
      int gr0 = bm + m*16 + lhi*4;
      #pragma unroll
      for (int r = 0; r < 4; ++r) {
        int t = gr0 + r;
        float v = acc[m][r];
        float pv = __shfl_xor(v, 1);
        float pos = (float)(half ? (t >> 5) : (t & 31));
        float ang = pos * inv;
        float cs = __cosf(ang), sn = __sinf(ang);
        float res = odd ? (pv*sn + v*cs) : (v*cs - pv*sn);
        res *= scl;
        ushort hh, ll; split2(res, hh, ll);
        size_t o = (size_t)h*32768 + (size_t)t*32 + d;
        dH[o] = hh; dL[o] = ll;
      }
    }
  } else {
    int c = gc - 512;
    int h = c >> 5, d = c & 31;
    #pragma unroll
    for (int m = 0; m < 4; ++m) {
      int t0 = bm + m*16 + lhi*4;
      ushort4v vh, vl;
      #pragma unroll
      for (int r = 0; r < 4; ++r) {
        ushort hh, ll; split2(acc[m][r], hh, ll);
        vh[r] = hh; vl[r] = ll;
      }
      size_t o = (size_t)h*32768 + (size_t)d*1024 + t0;
      *(ushort4v*)(VtH + o) = vh;
      *(ushort4v*)(VtL + o) = vl;
    }
  }
}

// ---------------------------------------------------------------------------
// Flash attention: block=(h,qt), 8 waves x 4 K-tiles, LDS merge.
// ---------------------------------------------------------------------------
__global__ __launch_bounds__(512,1)
void k_fattn(const ushort* __restrict__ QsH, const ushort* __restrict__ QsL,
             const ushort* __restrict__ KsH, const ushort* __restrict__ KsL,
             const ushort* __restrict__ VtH, const ushort* __restrict__ VtL,
             ushort* __restrict__ oH, ushort* __restrict__ oL) {
  __shared__ float sM[8][64], sL[8][64];
  __shared__ float sO[8][64][16];
  int h  = blockIdx.x >> 5;
  int qt = blockIdx.x & 31;
  int tid = threadIdx.x;
  int wv = tid >> 6, lane = tid & 63;
  int l31 = lane & 31, lhi = (lane >> 5) & 1;

  const size_t qoff = ((size_t)h*1024 + qt*32 + l31)*32 + lhi*8;
  short8 qh = *(const short8*)(QsH + qoff);
  short8 ql = *(const short8*)(QsL + qoff);

  f32x16 oacc;
  #pragma unroll
  for (int r = 0; r < 16; ++r) oacc[r] = 0.f;
  float mrun = -INFINITY, lrun = 0.f;

  for (int kt = wv*4; kt < wv*4 + 4; ++kt) {
    const size_t koff = ((size_t)h*1024 + kt*32 + l31)*32 + lhi*8;
    short8 kh = *(const short8*)(KsH + koff);
    short8 kl = *(const short8*)(KsL + koff);
    const size_t voff = ((size_t)h*32 + l31)*1024 + kt*32 + lhi*8;
    short8 vh0 = *(const short8*)(VtH + voff);
    short8 vl0 = *(const short8*)(VtL + voff);
    short8 vh1 = *(const short8*)(VtH + voff + 16);
    short8 vl1 = *(const short8*)(VtL + voff + 16);

    f32x16 s;
    #pragma unroll
    for (int r = 0; r < 16; ++r) s[r] = 0.f;
    s = MFMA32(kh, qh, s);
    s = MFMA32(kl, qh, s);
    s = MFMA32(kh, ql, s);

    float mloc = s[0];
    #pragma unroll
    for (int r = 1; r < 16; ++r) mloc = fmaxf(mloc, s[r]);
    mloc = fmaxf(mloc, __shfl_xor(mloc, 32));
    float mnew = fmaxf(mrun, mloc);
    float fsc = __expf(mrun - mnew);
    float p[16]; float ssum = 0.f;
    #pragma unroll
    for (int r = 0; r < 16; ++r) { p[r] = __expf(s[r] - mnew); ssum += p[r]; }
    ssum += __shfl_xor(ssum, 32);
    lrun = lrun * fsc + ssum;
    mrun = mnew;
    #pragma unroll
    for (int r = 0; r < 16; ++r) oacc[r] *= fsc;

    unsigned wh[8], wl[8];
    #pragma unroll
    for (int i = 0; i < 8; ++i) {
      ushort h0,l0,h1,l1;
      split2(p[2*i], h0, l0);
      split2(p[2*i+1], h1, l1);
      wh[i] = (unsigned)h0 | ((unsigned)h1 << 16);
      wl[i] = (unsigned)l0 | ((unsigned)l1 << 16);
    }
    unsigned pwh[8], pwl[8];
    #pragma unroll
    for (int i = 0; i < 8; ++i) {
      pwh[i] = (unsigned)__shfl_xor((int)wh[i], 32);
      pwl[i] = (unsigned)__shfl_xor((int)wl[i], 32);
    }
    union U { unsigned u[4]; short8 s; };
    U bh0, bl0, bh1, bl1;
    bh0.u[0] = lhi ? pwh[2] : wh[0];  bh0.u[1] = lhi ? pwh[3] : wh[1];
    bh0.u[2] = lhi ? wh[2]  : pwh[0]; bh0.u[3] = lhi ? wh[3]  : pwh[1];
    bl0.u[0] = lhi ? pwl[2] : wl[0];  bl0.u[1] = lhi ? pwl[3] : wl[1];
    bl0.u[2] = lhi ? wl[2]  : pwl[0]; bl0.u[3] = lhi ? wl[3]  : pwl[1];
    bh1.u[0] = lhi ? pwh[6] : wh[4];  bh1.u[1] = lhi ? pwh[7] : wh[5];
    bh1.u[2] = lhi ? wh[6]  : pwh[4]; bh1.u[3] = lhi ? wh[7]  : pwh[5];
    bl1.u[0] = lhi ? pwl[6] : wl[4];  bl1.u[1] = lhi ? pwl[7] : wl[5];
    bl1.u[2] = lhi ? wl[6]  : pwl[4]; bl1.u[3] = lhi ? wl[7]  : pwl[5];

    oacc = MFMA32(vh0, bh0.s, oacc);
    oacc = MFMA32(vl0, bh0.s, oacc);
    oacc = MFMA32(vh0, bl0.s, oacc);
    oacc = MFMA32(vh1, bh1.s, oacc);
    oacc = MFMA32(vl1, bh1.s, oacc);
    oacc = MFMA32(vh1, bl1.s, oacc);
  }

  sM[wv][lane] = mrun;
  sL[wv][lane] = lrun;
  #pragma unroll
  for (int r = 0; r < 16; ++r) sO[wv][lane][r] = oacc[r];
  __syncthreads();

  if (wv == 0) {
    float M = sM[0][lane];
    #pragma unroll
    for (int w = 1; w < 8; ++w) M = fmaxf(M, sM[w][lane]);
    float L = 0.f;
    float O[16];
    #pragma unroll
    for (int r = 0; r < 16; ++r) O[r] = 0.f;
    #pragma unroll
    for (int w = 0; w < 8; ++w) {
      float f = __expf(sM[w][lane] - M);
      L += sL[w][lane] * f;
      #pragma unroll
      for (int r = 0; r < 16; ++r) O[r] += sO[w][lane][r] * f;
    }
    float inv = 1.0f / L;
    int t = qt*32 + l31;
    #pragma unroll
    for (int r = 0; r < 16; ++r) {
      int d = (r & 3) + 8*(r >> 2) + 4*lhi;
      float v = O[r] * inv;
      ushort hh, ll; split2(v, hh, ll);
      oH[(size_t)t*DIMD + h*32 + d] = hh;
      oL[(size_t)t*DIMD + h*32 + d] = ll;
    }
  }
}

// ---------------------------------------------------------------------------
// Fused gate/value GEMM + SiLU, with fused RMSNORM on A
// ---------------------------------------------------------------------------
__global__ __launch_bounds__(256,2)
void k_ffgv(const float* __restrict__ tok, const float* __restrict__ nw,
            const ushort* __restrict__ Bh, const ushort* __restrict__ Bl,
            ushort* __restrict__ fH, ushort* __restrict__ fL) {
  __shared__ ushort sAh[64*40], sAl[64*40];
  __shared__ ushort sGh[64*40], sGl[64*40];
  __shared__ ushort sVh[64*40], sVl[64*40];
  __shared__ float sp[64][4];
  __shared__ float snorm[64];
  __shared__ float swt[256];
  int tid = threadIdx.x;
  int wave = tid >> 6, lane = tid & 63, l15 = lane & 15, lhi = lane >> 4;
  int bm = blockIdx.y * 64, bn = blockIdx.x * 64;
  int sr = tid >> 2, sg = (tid & 3) * 8;
  const size_t goff = (size_t)(bn + sr) * 256 + sg;
  const size_t voff = (size_t)(1024 + bn + sr) * 256 + sg;

  swt[tid] = nw[tid];
  {
    int r = tid >> 2, p = tid & 3;
    const float* row = tok + (size_t)(bm + r)*256 + p*64;
    float s = 0.f;
    for (int j = 0; j < 64; j += 4) {
      f32x4 v = *(const f32x4*)(row + j);
      s += v[0]*v[0] + v[1]*v[1] + v[2]*v[2] + v[3]*v[3];
    }
    sp[r][p] = s;
  }
  __syncthreads();
  if (tid < 64)
    snorm[tid] = rsqrtf((sp[tid][0]+sp[tid][1]+sp[tid][2]+sp[tid][3]) * (1.0f/256.0f) + 1e-6f);

  f32x4 accg[4], accv[4];
  #pragma unroll
  for (int m = 0; m < 4; ++m) { accg[m] = (f32x4){0.f,0.f,0.f,0.f}; accv[m] = accg[m]; }

  for (int k0 = 0; k0 < 256; k0 += 32) {
    __syncthreads();
    {
      float nrm = snorm[sr];
      const float* src = tok + (size_t)(bm + sr)*256 + k0 + sg;
      ushort8 vh, vl;
      #pragma unroll
      for (int j = 0; j < 8; ++j) {
        float v = src[j] * nrm * swt[k0 + sg + j];
        ushort hh, ll; split2(v, hh, ll);
        vh[j] = hh; vl[j] = ll;
      }
      *(ushort8*)(sAh + sr*40 + sg) = vh;
      *(ushort8*)(sAl + sr*40 + sg) = vl;
    }
    *(ushort8*)(sGh + sr*40 + sg) = *(const ushort8*)(Bh + goff + k0);
    *(ushort8*)(sGl + sr*40 + sg) = *(const ushort8*)(Bl + goff + k0);
    *(ushort8*)(sVh + sr*40 + sg) = *(const ushort8*)(Bh + voff + k0);
    *(ushort8*)(sVl + sr*40 + sg) = *(const ushort8*)(Bl + voff + k0);
    __syncthreads();
    short8 ah[4], al[4];
    #pragma unroll
    for (int m = 0; m < 4; ++m) {
      int r = m*16 + l15;
      ah[m] = *(const short8*)(sAh + r*40 + lhi*8);
      al[m] = *(const short8*)(sAl + r*40 + lhi*8);
    }
    int rb = wave*16 + l15;
    short8 gh = *(const short8*)(sGh + rb*40 + lhi*8);
    short8 gl = *(const short8*)(sGl + rb*40 + lhi*8);
    short8 vh = *(const short8*)(sVh + rb*40 + lhi*8);
    short8 vl = *(const short8*)(sVl + rb*40 + lhi*8);
    #pragma unroll
    for (int m = 0; m < 4; ++m) {
      accg[m] = MFMA(ah[m], gh, accg[m]);
      accg[m] = MFMA(al[m], gh, accg[m]);
      accg[m] = MFMA(ah[m], gl, accg[m]);
      accv[m] = MFMA(ah[m], vh, accv[m]);
      accv[m] = MFMA(al[m], vh, accv[m]);
      accv[m] = MFMA(ah[m], vl, accv[m]);
    }
  }

  int gc = bn + wave*16 + l15;
  #pragma unroll
  for (int m = 0; m < 4; ++m) {
    int gr0 = bm + m*16 + lhi*4;
    #pragma unroll
    for (int r = 0; r < 4; ++r) {
      float g = accg[m][r], v = accv[m][r];
      float s = g / (1.0f + expf(-g));
      float rr = s * v;
      ushort hh, ll; split2(rr, hh, ll);
      size_t idx = (size_t)(gr0 + r)*1024 + gc;
      fH[idx] = hh; fL[idx] = ll;
    }
  }
}

// ---------------------------------------------------------------------------
// Fused query head (best-measured round-7 version): 512 threads / 8 waves;
// split activations; B double-buffered from global; MFMA GEMV vs dw2t.
// ---------------------------------------------------------------------------
__global__ __launch_bounds__(512,5)
void k_qhead(const float* __restrict__ qpos, const float* __restrict__ quinf,
             const float* __restrict__ qsdf, const float* __restrict__ qgrad,
             const float* __restrict__ projCL,
             const ushort* __restrict__ pw1tH, const ushort* __restrict__ pw1tL,
             const float* __restrict__ pb1,
             const ushort* __restrict__ wcH, const ushort* __restrict__ wcL,
             const float* __restrict__ b2eff,
             const ushort* __restrict__ dw2tH, const ushort* __restrict__ dw2tL,
             const float* __restrict__ db2,
             float* __restrict__ out) {
  __shared__ ushort sPinH[QN*72], sPinL[QN*72];
  __shared__ ushort sH1H[QN*264], sH1L[QN*264];
  __shared__ float  sXY[QN][2];
  __shared__ float  sRed[8][128];

  int tid = threadIdx.x;
  int w = tid >> 6, lane = tid & 63, l15 = lane & 15, lhi = lane >> 4;
  int q0 = blockIdx.x * QN;

  if (tid < QN) {
    int qg = q0 + tid;
    float x = qpos[(size_t)qg*2 + 0], y = qpos[(size_t)qg*2 + 1];
    float xn = fminf(fmaxf(2.0f*(x + 2.0f)/6.0f - 1.0f, -1.0f), 1.0f);
    float yn = fminf(fmaxf(2.0f*(y + 1.5f)/3.0f - 1.0f, -1.0f), 1.0f);
    sXY[tid][0] = xn; sXY[tid][1] = yn;
  }
  __syncthreads();

  {
    int q = tid >> 4;
    int j0 = (tid & 15) * 4;
    int qg = q0 + q;
    float xn = sXY[q][0], yn = sXY[q][1];
    #pragma unroll
    for (int jj = 0; jj < 4; ++jj) {
      int j = j0 + jj;
      float v = 0.f;
      if (j == 0) v = xn;
      else if (j == 1) v = yn;
      else if (j < 42) {
        int z = j - 2;
        int coord = z / 20;
        int ww = z % 20;
        int isCos = ww / 10;
        int fi = ww % 10;
        float f = ldexpf(3.14159265358979323846f, fi);
        float a = (coord ? yn : xn) * f;
        v = isCos ? __cosf(a) : __sinf(a);
      }
      else if (j < 44) v = quinf[(size_t)qg*2 + (j-42)];
      else if (j == 44) v = qsdf[qg];
      else if (j < 47) v = qgrad[(size_t)qg*2 + (j-45)];
      ushort h, l; split2(v, h, l);
      sPinH[q*72 + j] = h; sPinL[q*72 + j] = l;
    }
  }
  __syncthreads();

  f32x4 acc[2][2];
  #pragma unroll
  for (int m = 0; m < 2; ++m)
    #pragma unroll
    for (int n = 0; n < 2; ++n) acc[m][n] = (f32x4){0.f,0.f,0.f,0.f};

  // phase 1: h1 = pin @ pw1t (K=64)
  #pragma unroll
  for (int ks = 0; ks < 2; ++ks) {
    short8 bh[2], bl[2];
    #pragma unroll
    for (int n = 0; n < 2; ++n) {
      int r = w*32 + n*16 + l15;
      bh[n] = *(const short8*)(pw1tH + r*64 + ks*32 + lhi*8);
      bl[n] = *(const short8*)(pw1tL + r*64 + ks*32 + lhi*8);
    }
    short8 ah[2], al[2];
    #pragma unroll
    for (int m = 0; m < 2; ++m) {
      int r = m*16 + l15;
      ah[m] = *(const short8*)(sPinH + r*72 + ks*32 + lhi*8);
      al[m] = *(const short8*)(sPinL + r*72 + ks*32 + lhi*8);
    }
    #pragma unroll
    for (int m = 0; m < 2; ++m)
      #pragma unroll
      for (int n = 0; n < 2; ++n) {
        acc[m][n] = MFMA(ah[m], bh[n], acc[m][n]);
        acc[m][n] = MFMA(al[m], bh[n], acc[m][n]);
        acc[m][n] = MFMA(ah[m], bl[n], acc[m][n]);
      }
  }
  // h1 epilogue
  #pragma unroll
  for (int m = 0; m < 2; ++m) {
    #pragma unroll
    for (int n = 0; n < 2; ++n) {
      int col = w*32 + n*16 + l15;
      float bv = pb1[col];
      #pragma unroll
      for (int r = 0; r < 4; ++r) {
        int row = m*16 + lhi*4 + r;
        float v = fmaxf(acc[m][n][r] + bv, 0.f);
        ushort h, l; split2(v, h, l);
        sH1H[row*264 + col] = h;
        sH1L[row*264 + col] = l;
      }
      acc[m][n] = (f32x4){0.f,0.f,0.f,0.f};
    }
  }
  __syncthreads();

  // phase 2: h1 @ Wcomb (K=256), B double-buffered from global
  short8 pbh[2], pbl[2];
  #pragma unroll
  for (int n = 0; n < 2; ++n) {
    int r = w*32 + n*16 + l15;
    pbh[n] = *(const short8*)(wcH + (size_t)r*256 + lhi*8);
    pbl[n] = *(const short8*)(wcL + (size_t)r*256 + lhi*8);
  }
  #pragma unroll
  for (int ks = 0; ks < 8; ++ks) {
    short8 bh[2], bl[2];
    #pragma unroll
    for (int n = 0; n < 2; ++n) { bh[n] = pbh[n]; bl[n] = pbl[n]; }
    if (ks < 7) {
      #pragma unroll
      for (int n = 0; n < 2; ++n) {
        int r = w*32 + n*16 + l15;
        pbh[n] = *(const short8*)(wcH + (size_t)r*256 + (ks+1)*32 + lhi*8);
        pbl[n] = *(const short8*)(wcL + (size_t)r*256 + (ks+1)*32 + lhi*8);
      }
    }
    short8 ah[2], al[2];
    #pragma unroll
    for (int m = 0; m < 2; ++m) {
      int r = m*16 + l15;
      ah[m] = *(const short8*)(sH1H + r*264 + ks*32 + lhi*8);
      al[m] = *(const short8*)(sH1L + r*264 + ks*32 + lhi*8);
    }
    #pragma unroll
    for (int m = 0; m < 2; ++m)
      #pragma unroll
      for (int n = 0; n < 2; ++n) {
        acc[m][n] = MFMA(ah[m], bh[n], acc[m][n]);
        acc[m][n] = MFMA(al[m], bh[n], acc[m][n]);
        acc[m][n] = MFMA(ah[m], bl[n], acc[m][n]);
      }
  }
  __syncthreads();  // all waves finished reading sH1 (phase-2 A)

  // h2 epilogue: bilinear + b2eff + relu, split -> reuse sH1 as h2
  #pragma unroll
  for (int m = 0; m < 2; ++m) {
    #pragma unroll
    for (int r = 0; r < 4; ++r) {
      int q = m*16 + lhi*4 + r;
      float xn = sXY[q][0], yn = sXY[q][1];
      float px = (xn + 1.0f) * 0.5f * 63.0f;
      float py = (yn + 1.0f) * 0.5f * 63.0f;
      float x0 = fminf(fmaxf(floorf(px), 0.f), 63.f);
      float y0 = fminf(fmaxf(floorf(py), 0.f), 63.f);
      float wx = px - x0, wy = py - y0;
      int x0i = (int)x0, y0i = (int)y0;
      int x1i = min(x0i + 1, 63), y1i = min(y0i + 1, 63);
      const float* p00 = projCL + (size_t)(y0i*64 + x0i)*256;
      const float* p01 = projCL + (size_t)(y0i*64 + x1i)*256;
      const float* p10 = projCL + (size_t)(y1i*64 + x0i)*256;
      const float* p11 = projCL + (size_t)(y1i*64 + x1i)*256;
      float w00 = (1.f-wx)*(1.f-wy), w01 = wx*(1.f-wy), w10 = (1.f-wx)*wy, w11 = wx*wy;
      #pragma unroll
      for (int n = 0; n < 2; ++n) {
        int col = w*32 + n*16 + l15;
        float bil = w00*p00[col] + w01*p01[col] + w10*p10[col] + w11*p11[col];
        float v = fmaxf(acc[m][n][r] + b2eff[col] + bil, 0.f);
        ushort hh, ll; split2(v, hh, ll);
        sH1H[q*264 + col] = hh;
        sH1L[q*264 + col] = ll;
      }
    }
  }
  __syncthreads();

  // GEMV via MFMA: wave w contracts k-slice [w*32, w*32+32)
  {
    short8 ah2[2], al2[2];
    #pragma unroll
    for (int m = 0; m < 2; ++m) {
      int r = m*16 + l15;
      ah2[m] = *(const short8*)(sH1H + r*264 + w*32 + lhi*8);
      al2[m] = *(const short8*)(sH1L + r*264 + w*32 + lhi*8);
    }
    short8 bh2 = *(const short8*)(dw2tH + (size_t)l15*256 + w*32 + lhi*8);
    short8 bl2 = *(const short8*)(dw2tL + (size_t)l15*256 + w*32 + lhi*8);
    f32x4 c[2];
    #pragma unroll
    for (int m = 0; m < 2; ++m) {
      c[m] = (f32x4){0.f,0.f,0.f,0.f};
      c[m] = MFMA(ah2[m], bh2, c[m]);
      c[m] = MFMA(al2[m], bh2, c[m]);
      c[m] = MFMA(ah2[m], bl2, c[m]);
    }
    if (l15 < 4) {
      #pragma unroll
      for (int m = 0; m < 2; ++m)
        #pragma unroll
        for (int r = 0; r < 4; ++r)
          sRed[w][(m*16 + lhi*4 + r)*4 + l15] = c[m][r];
    }
  }
  __syncthreads();

  if (tid < 128) {
    int q = tid >> 2, d = tid & 3;
    float a = db2[d];
    #pragma unroll
    for (int ww = 0; ww < 8; ++ww) a += sRed[ww][q*4 + d];
    out[(size_t)(q0 + q)*4 + d] = a;
  }
}

// ---------------------------------------------------------------------------
extern "C" void kernel_launch(void* const* d_in, const int* in_sizes, int n_in,
                              void* d_out, int out_size, void* d_ws, size_t ws_size,
                              hipStream_t stream) {
  (void)in_sizes; (void)n_in; (void)out_size; (void)ws_size;
  const float* points     = (const float*)d_in[0];
  const float* grd        = (const float*)d_in[1];
  const float* qpos       = (const float*)d_in[2];
  const float* quinf      = (const float*)d_in[3];
  const float* qsdf       = (const float*)d_in[4];
  const float* qgrad      = (const float*)d_in[5];
  const float* enc_w1     = (const float*)d_in[6];
  const float* enc_b1     = (const float*)d_in[7];
  const float* enc_w2     = (const float*)d_in[8];
  const float* enc_b2     = (const float*)d_in[9];
  const float* inproj_w   = (const float*)d_in[10];
  const float* inproj_b   = (const float*)d_in[11];
  const float* patch_w    = (const float*)d_in[12];
  const float* patch_b    = (const float*)d_in[13];
  const float* norm1_w    = (const float*)d_in[14];
  const float* qkv_w      = (const float*)d_in[15];
  const float* attnproj_w = (const float*)d_in[16];
  const float* norm2_w    = (const float*)d_in[17];
  const float* gate_w     = (const float*)d_in[18];
  const float* value_w    = (const float*)d_in[19];
  const float* ffnout_w   = (const float*)d_in[20];
  const float* unpatch_w  = (const float*)d_in[21];
  const float* unpatch_b  = (const float*)d_in[22];
  const float* pw1        = (const float*)d_in[23];
  const float* pb1        = (const float*)d_in[24];
  const float* pw2        = (const float*)d_in[25];
  const float* pb2        = (const float*)d_in[26];
  const float* dw1        = (const float*)d_in[27];
  const float* db1        = (const float*)d_in[28];
  const float* dw2        = (const float*)d_in[29];
  const float* db2        = (const float*)d_in[30];
  float* out = (float*)d_out;

  char* base = (char*)d_ws;
  size_t off = 0;
  auto alloc = [&](size_t bytes) -> void* {
    void* p = base + off; off += (bytes + 255) & ~(size_t)255; return p;
  };

  // ---- persistent small transposed weights
  ushort* inprojTH = (ushort*)alloc(32768*2);   ushort* inprojTL = (ushort*)alloc(32768*2);
  ushort* patchTH  = (ushort*)alloc(262144*2);  ushort* patchTL  = (ushort*)alloc(262144*2);
  ushort* upTH     = (ushort*)alloc(262144*2);  ushort* upTL     = (ushort*)alloc(262144*2);
  ushort* pw1TH    = (ushort*)alloc(16384*2);   ushort* pw1TL    = (ushort*)alloc(16384*2);
  ushort* wcTH     = (ushort*)alloc(65536*2);   ushort* wcTL     = (ushort*)alloc(65536*2);
  ushort* dw1aTH   = (ushort*)alloc(65536*2);   ushort* dw1aTL   = (ushort*)alloc(65536*2);
  ushort* dw2tH    = (ushort*)alloc(4096*2);    ushort* dw2tL    = (ushort*)alloc(4096*2);
  float*  Wcomb    = (float*)alloc(65536*4);
  float*  b2eff    = (float*)alloc(256*4);

  // ---- binning
  int*   cellcnt   = (int*)alloc(NCELL*4);
  int*   cellstart = (int*)alloc((NCELL+1)*4);
  int*   cursor    = (int*)alloc(NCELL*4);
  float* bpx       = (float*)alloc(NPTS*4);
  float* bpy       = (float*)alloc(NPTS*4);
  int*   bpi       = (int*)alloc(NPTS*4);

  // ---- ALL transformer-layer weights (split once)
  ushort* lwH = (ushort*)alloc((size_t)NLAY*1048576*2);
  ushort* lwL = (ushort*)alloc((size_t)NLAY*1048576*2);
  const size_t qkvO = 0, apO = 196608, gateO = 262144, foO = 786432;

  // ---- activations
  ushort* featcH = (ushort*)alloc(524288*2);   ushort* featcL = (ushort*)alloc(524288*2);
  ushort* xpH = (ushort*)alloc(1048576*2);     // xp / ff / pr
  ushort* xpL = (ushort*)alloc(1048576*2);
  float*  tok = (float*)alloc(262144*4);
  ushort* tkH = (ushort*)alloc(262144*2);
  ushort* tkL = (ushort*)alloc(262144*2);
  ushort* oH  = (ushort*)alloc(262144*2);
  ushort* oL  = (ushort*)alloc(262144*2);
  float*  unionBuf = (float*)alloc(2097152*4); // Qs..Vt planes / projCL
  float*  projCL = unionBuf + 1048576;

  ushort* QsH = (ushort*)unionBuf;
  ushort* QsL = QsH + 262144;
  ushort* KsH = QsH + 2*262144;
  ushort* KsL = QsH + 3*262144;
  ushort* VtH = QsH + 4*262144;
  ushort* VtL = QsH + 5*262144;

  ushort* ffH = xpH;  ushort* ffL = xpL;
  ushort* prH = xpH;  ushort* prL = xpL;

  // ---- prep
  k_gemm<<<dim3(8,8), 256, 0, stream>>>(pw2, dw1 + 256*256, Wcomb, 256, 256, 512);
  k_beff<<<8, 256, 0, stream>>>(db1, pb2, dw1, b2eff);
  k_dw2t<<<1, 256, 0, stream>>>(dw2, dw2tH, dw2tL);

  auto addw = [](STable& t, int& cb, const float* src, ushort* dh, ushort* dl,
                 int K, int N, int Kp) {
    SDesc& s = t.d[t.nw]; s.src = src; s.dh = dh; s.dl = dl;
    s.K = K; s.N = N; s.Kp = Kp; s.blk0 = cb;
    cb += (Kp >> 5) * (N >> 5); t.nw++;
  };

  {
    STable gt; gt.nw = 0; int cb = 0;
    addw(gt, cb, inproj_w, inprojTH, inprojTL, 128, 256, 128);
    addw(gt, cb, patch_w,  patchTH,  patchTL,  1024, 256, 1024);
    addw(gt, cb, unpatch_w, upTH, upTL, 256, 1024, 256);
    addw(gt, cb, pw1,   pw1TH,  pw1TL,  47, 256, 64);
    addw(gt, cb, Wcomb, wcTH,   wcTL,   256, 256, 256);
    addw(gt, cb, dw1,   dw1aTH, dw1aTL, 256, 256, 256);
    for (int l = 0; l < NLAY; ++l) {
      size_t lb = (size_t)l*1048576;
      addw(gt, cb, qkv_w      + (size_t)l*196608, lwH + lb + qkvO,  lwL + lb + qkvO,  256, 768, 256);
      addw(gt, cb, attnproj_w + (size_t)l*65536,  lwH + lb + apO,   lwL + lb + apO,   256, 256, 256);
      addw(gt, cb, gate_w     + (size_t)l*262144, lwH + lb + gateO,          lwL + lb + gateO,          256, 1024, 256);
      addw(gt, cb, value_w    + (size_t)l*262144, lwH + lb + gateO + 262144, lwL + lb + gateO + 262144, 256, 1024, 256);
      addw(gt, cb, ffnout_w   + (size_t)l*262144, lwH + lb + foO,   lwL + lb + foO,   1024, 256, 1024);
    }
    k_splitT_all<<<cb, 256, 0, stream>>>(gt);
  }

  k_zero<<<4, 256, 0, stream>>>(cellcnt);
  k_bincount<<<(NPTS+255)/256, 256, 0, stream>>>(points, cellcnt);
  k_prefix<<<1, 1024, 0, stream>>>(cellcnt, cellstart, cursor);
  k_scatter<<<(NPTS+255)/256, 256, 0, stream>>>(points, cursor, bpx, bpy, bpi);

  // ---- encode + patchify
  k_encode<<<dim3(GRD, 2), 256, 0, stream>>>(bpx, bpy, bpi, cellstart, grd,
                                             enc_w1, enc_b1, enc_w2, enc_b2, featcH, featcL);
  k_inproj<<<dim3(4,64), 256, 0, stream>>>(featcH, featcL, inprojTH, inprojTL, inproj_b, xpH, xpL);
  k_mgemm64<true,false,false,2><<<dim3(4,32), 256, 0, stream>>>(xpH, xpL, patchTH, patchTL, patch_b, nullptr, tok, TOK, 256, 1024, nullptr, nullptr);

  // ---- transformer
  for (int l = 0; l < NLAY; ++l) {
    size_t lb = (size_t)l*1048576;
    k_qkvrope<<<dim3(12,16), 256, 0, stream>>>(tok, norm1_w + (size_t)l*DIMD,
                                               lwH + lb + qkvO, lwL + lb + qkvO,
                                               QsH, QsL, KsH, KsL, VtH, VtL);
    k_fattn<<<256, 512, 0, stream>>>(QsH, QsL, KsH, KsL, VtH, VtL, oH, oL);
    k_mgemm64<false,true,false,2><<<dim3(4,32), 256, 0, stream>>>(oH, oL, lwH + lb + apO, lwL + lb + apO, nullptr, tok, tok, TOK, 256, 256, nullptr, nullptr);
    k_ffgv<<<dim3(16,16), 256, 0, stream>>>(tok, norm2_w + (size_t)l*DIMD,
                                            lwH + lb + gateO, lwL + lb + gateO, ffH, ffL);
    if (l < NLAY-1)
      k_mgemm64<false,true,false,2><<<dim3(4,32), 256, 0, stream>>>(ffH, ffL, lwH + lb + foO, lwL + lb + foO, nullptr, tok, tok, TOK, 256, 1024, nullptr, nullptr);
    else
      k_mgemm64<false,true,true,2><<<dim3(4,32), 256, 0, stream>>>(ffH, ffL, lwH + lb + foO, lwL + lb + foO, nullptr, tok, tok, TOK, 256, 1024, tkH, tkL);
  }

  // ---- unpatch GEMM (fused permute) + grid projection
  k_upgemm<<<dim3(16,16), 256, 0, stream>>>(tkH, tkL, upTH, upTL, unpatch_b, prH, prL);
  k_mgemm64<false,false,false,4><<<dim3(4,64), 256, 0, stream>>>(prH, prL, dw1aTH, dw1aTL, nullptr, nullptr, projCL, GRD, 256, 256, nullptr, nullptr);

  // ---- query head
  k_qhead<<<NQ/QN, 512, 0, stream>>>(qpos, quinf, qsdf, qgrad, projCL,
      pw1TH, pw1TL, pb1, wcTH, wcTL, b2eff, dw2tH, dw2tL, db2, out);
}